// Round 18
// baseline (420.734 us; speedup 1.0000x reference)
//
#include <hip/hip_runtime.h>
#include <stdint.h>

#define B_   2
#define T_   2048
#define D_   2048
#define H_   16
#define KV_  8
#define DH_  128
#define NMEM 1024
#define WWIN 256
#define KSEL 8
#define BT   (B_*T_)
#define QKVSTR 4096   // merged qkv row stride (elements)

__constant__ const float kScale = 0.08838834764831845f; // DH^-0.5

typedef __attribute__((ext_vector_type(8))) short s16x8;
typedef __attribute__((ext_vector_type(4))) float f32x4;

__device__ inline unsigned short f2bf(float f) {
  union { float f; unsigned int u; } c; c.f = f;
  unsigned int u = c.u;
  unsigned int r = u + 0x7fffu + ((u >> 16) & 1u);
  return (unsigned short)(r >> 16);
}
__device__ inline float bf2f(unsigned short v) {
  union { unsigned int u; float f; } c; c.u = ((unsigned int)v) << 16;
  return c.f;
}
__device__ inline f32x4 fzero4() { f32x4 v; v[0]=0.f; v[1]=0.f; v[2]=0.f; v[3]=0.f; return v; }

// ---------------- merged fp32 -> bf16 conversion (6 tensors, one launch) ----------------
__global__ __launch_bounds__(256) void conv6_kernel(const float* __restrict__ hs,
                                                    const float* __restrict__ Wq,
                                                    const float* __restrict__ Wk,
                                                    const float* __restrict__ Wv,
                                                    const float* __restrict__ mem,
                                                    const float* __restrict__ Wo,
                                                    unsigned short* __restrict__ hs_bf,
                                                    unsigned short* __restrict__ wbig,
                                                    unsigned short* __restrict__ mem_bf,
                                                    unsigned short* __restrict__ wo_bf) {
  int blk = blockIdx.x, tid = threadIdx.x;
  const float* src;
  unsigned short* dst;
  int i;
  if (blk < 8192)       { src = hs;  dst = hs_bf;  i = blk; }
  else if (blk < 12288) { src = Wq;  dst = wbig;   i = blk - 8192; }
  else if (blk < 14336) { src = Wk;  dst = wbig + (size_t)D_ * D_; i = blk - 12288; }
  else if (blk < 16384) { src = Wv;  dst = wbig + (size_t)D_ * D_ + (size_t)KV_ * DH_ * D_; i = blk - 14336; }
  else if (blk < 20480) { src = mem; dst = mem_bf; i = blk - 16384; }
  else                  { src = Wo;  dst = wo_bf;  i = blk - 20480; }
  size_t idx = (size_t)i * 256 + tid;
  float4 v = ((const float4*)src)[idx];
  uint2 o;
  o.x = (unsigned)f2bf(v.x) | ((unsigned)f2bf(v.y) << 16);
  o.y = (unsigned)f2bf(v.z) | ((unsigned)f2bf(v.w) << 16);
  ((uint2*)dst)[idx] = o;
}

// ================= 256x256 8-phase GEMM (T2+T3+T4+T5) =================
#define AOFF(buf, half) ((buf)*32768 + (half)*16384)
#define BOFF(buf, half) (65536 + (buf)*32768 + (half)*16384)

#define PH_MFMA(P, BF) \
  { \
    _Pragma("unroll") \
    for (int mi = 0; mi < 2; ++mi) { \
      _Pragma("unroll") \
      for (int ni = 0; ni < 4; ++ni) { \
        acc[P][mi][ni] = __builtin_amdgcn_mfma_f32_16x16x32_bf16(af[mi][0], BF[ni][0], acc[P][mi][ni], 0, 0, 0); \
        acc[P][mi][ni] = __builtin_amdgcn_mfma_f32_16x16x32_bf16(af[mi][1], BF[ni][1], acc[P][mi][ni], 0, 0, 0); \
      } \
    } \
  }

template<int MODE>
__global__ __launch_bounds__(512, 2) void gemm256(const unsigned short* __restrict__ A,
                                                  const unsigned short* __restrict__ Bw,
                                                  int N, int K, int lda, int ldc,
                                                  unsigned short* __restrict__ Cb,
                                                  const float* __restrict__ g,
                                                  const unsigned short* __restrict__ omem,
                                                  float* __restrict__ dout) {
  __shared__ __align__(16) char lds[131072];
  const int tid = threadIdx.x;
  const int wv = tid >> 6, lane = tid & 63;
  const int l15 = lane & 15, lg = lane >> 4;
  const int wr = wv >> 1, wc = wv & 1;
  const int gx = gridDim.x;
  const int nwg = gx * gridDim.y;
  const int flat = blockIdx.y * gx + blockIdx.x;
  const int chunk = nwg >> 3;
  const int wg = (flat & 7) * chunk + (flat >> 3);
  const int bx = wg % gx, by = wg / gx;
  const int m0 = by * 256, n0 = bx * 256;
  const int NT = K >> 6;

  auto stage_half = [&](const unsigned short* base, int stride, int row0, int koff, int ldsoff) {
#pragma unroll
    for (int ld = 0; ld < 2; ++ld) {
      int s = ld * 512 + tid;
      int row = s >> 3, cs = s & 7;
      int cg = cs ^ (row & 7);
      const unsigned short* src = base + (size_t)(row0 + row) * stride + koff + cg * 8;
      __builtin_amdgcn_global_load_lds((const __attribute__((address_space(1))) void*)src,
          (__attribute__((address_space(3))) void*)(lds + ldsoff + ld * 8192 + wv * 1024), 16, 0, 0);
    }
  };
  auto rdA = [&](int buf, int half, int mi, int kk) -> s16x8 {
    int r = wr * 32 + mi * 16 + l15;
    int slot = (kk * 4 + lg) ^ (r & 7);
    return *(const s16x8*)(lds + AOFF(buf, half) + r * 128 + slot * 16);
  };
  auto rdB = [&](int buf, int half, int ni, int kk) -> s16x8 {
    int r = wc * 64 + ni * 16 + l15;
    int slot = (kk * 4 + lg) ^ (r & 7);
    return *(const s16x8*)(lds + BOFF(buf, half) + r * 128 + slot * 16);
  };

  f32x4 acc[4][2][4];
#pragma unroll
  for (int p = 0; p < 4; ++p)
#pragma unroll
    for (int mi = 0; mi < 2; ++mi)
#pragma unroll
      for (int ni = 0; ni < 4; ++ni) acc[p][mi][ni] = fzero4();

  stage_half(A,  lda, m0,       0,  AOFF(0, 0));
  stage_half(Bw, K,   n0,       0,  BOFF(0, 0));
  stage_half(A,  lda, m0 + 128, 0,  AOFF(0, 1));
  stage_half(Bw, K,   n0 + 128, 0,  BOFF(0, 1));
  stage_half(A,  lda, m0,       64, AOFF(1, 0));
  stage_half(Bw, K,   n0,       64, BOFF(1, 0));
  stage_half(A,  lda, m0 + 128, 64, AOFF(1, 1));
  asm volatile("s_waitcnt vmcnt(6)" ::: "memory");
  __builtin_amdgcn_s_barrier();

  int cur = 0;
  for (int t = 0; t < NT; ++t, cur ^= 1) {
    const int nxt = cur ^ 1;
    s16x8 af[2][2], b0f[4][2], b1f[4][2];
#pragma unroll
    for (int mi = 0; mi < 2; ++mi) {
      af[mi][0] = rdA(cur, 0, mi, 0);
      af[mi][1] = rdA(cur, 0, mi, 1);
    }
#pragma unroll
    for (int ni = 0; ni < 4; ++ni) {
      b0f[ni][0] = rdB(cur, 0, ni, 0);
      b0f[ni][1] = rdB(cur, 0, ni, 1);
    }
    if (t + 1 < NT) stage_half(Bw, K, n0 + 128, (t + 1) * 64, BOFF(nxt, 1));
    __builtin_amdgcn_s_barrier();
    asm volatile("s_waitcnt lgkmcnt(0)" ::: "memory");
    __builtin_amdgcn_s_setprio(1);
    PH_MFMA(0, b0f);
    __builtin_amdgcn_s_setprio(0);
    __builtin_amdgcn_s_barrier();
#pragma unroll
    for (int ni = 0; ni < 4; ++ni) {
      b1f[ni][0] = rdB(cur, 1, ni, 0);
      b1f[ni][1] = rdB(cur, 1, ni, 1);
    }
    if (t + 2 < NT) stage_half(A, lda, m0, (t + 2) * 64, AOFF(cur, 0));
    __builtin_amdgcn_s_barrier();
    asm volatile("s_waitcnt lgkmcnt(0)" ::: "memory");
    __builtin_amdgcn_s_setprio(1);
    PH_MFMA(1, b1f);
    __builtin_amdgcn_s_setprio(0);
    __builtin_amdgcn_s_barrier();
#pragma unroll
    for (int mi = 0; mi < 2; ++mi) {
      af[mi][0] = rdA(cur, 1, mi, 0);
      af[mi][1] = rdA(cur, 1, mi, 1);
    }
    if (t + 2 < NT) stage_half(Bw, K, n0, (t + 2) * 64, BOFF(cur, 0));
    __builtin_amdgcn_s_barrier();
    asm volatile("s_waitcnt lgkmcnt(0)" ::: "memory");
    __builtin_amdgcn_s_setprio(1);
    PH_MFMA(2, b0f);
    __builtin_amdgcn_s_setprio(0);
    __builtin_amdgcn_s_barrier();
    if (t + 2 < NT) stage_half(A, lda, m0 + 128, (t + 2) * 64, AOFF(cur, 1));
    __builtin_amdgcn_s_barrier();
    asm volatile("s_waitcnt lgkmcnt(0)" ::: "memory");
    __builtin_amdgcn_s_setprio(1);
    PH_MFMA(3, b1f);
    __builtin_amdgcn_s_setprio(0);
    if (t < NT - 2) asm volatile("s_waitcnt vmcnt(6)" ::: "memory");
    else            asm volatile("s_waitcnt vmcnt(0)" ::: "memory");
    __builtin_amdgcn_s_barrier();
  }

#pragma unroll
  for (int p = 0; p < 4; ++p)
#pragma unroll
    for (int mi = 0; mi < 2; ++mi)
#pragma unroll
      for (int ni = 0; ni < 4; ++ni)
#pragma unroll
        for (int j = 0; j < 4; ++j) {
          int row_g = m0 + (p >> 1) * 128 + wr * 32 + mi * 16 + lg * 4 + j;
          int col_g = n0 + (p & 1) * 128 + wc * 64 + ni * 16 + l15;
          float v = acc[p][mi][ni][j];
          size_t o = (size_t)row_g * ldc + col_g;
          if constexpr (MODE == 0) {
            Cb[o] = f2bf(v);
          } else {
            float gv = g[row_g];
            dout[o] = gv * v + (1.f - gv) * bf2f(omem[o]);
          }
        }
}

// ================= 256x128 2-phase GEMM (full-machine grid for N=2048) =================
#define B2OFF(buf) (65536 + (buf)*16384)

__global__ __launch_bounds__(512, 2) void gemm256n(const unsigned short* __restrict__ A,
                                                   const unsigned short* __restrict__ Bw,
                                                   int N, int K, int lda, int ldc,
                                                   const float* __restrict__ g,
                                                   const unsigned short* __restrict__ omem,
                                                   float* __restrict__ dout) {
  __shared__ __align__(16) char lds[98304];
  const int tid = threadIdx.x;
  const int wv = tid >> 6, lane = tid & 63;
  const int l15 = lane & 15, lg = lane >> 4;
  const int wr = wv >> 1, wc = wv & 1;
  const int gx = gridDim.x;
  const int nwg = gx * gridDim.y;
  const int flat = blockIdx.y * gx + blockIdx.x;
  const int chunk = nwg >> 3;
  const int wg = (flat & 7) * chunk + (flat >> 3);
  const int bx = wg % gx, by = wg / gx;
  const int m0 = by * 256, n0 = bx * 128;
  const int NT = K >> 6;

  auto stage_half = [&](const unsigned short* base, int stride, int row0, int koff, int ldsoff) {
#pragma unroll
    for (int ld = 0; ld < 2; ++ld) {
      int s = ld * 512 + tid;
      int row = s >> 3, cs = s & 7;
      int cg = cs ^ (row & 7);
      const unsigned short* src = base + (size_t)(row0 + row) * stride + koff + cg * 8;
      __builtin_amdgcn_global_load_lds((const __attribute__((address_space(1))) void*)src,
          (__attribute__((address_space(3))) void*)(lds + ldsoff + ld * 8192 + wv * 1024), 16, 0, 0);
    }
  };
  auto rdA = [&](int buf, int half, int mi, int kk) -> s16x8 {
    int r = wr * 32 + mi * 16 + l15;
    int slot = (kk * 4 + lg) ^ (r & 7);
    return *(const s16x8*)(lds + AOFF(buf, half) + r * 128 + slot * 16);
  };
  auto rdB = [&](int buf, int ni, int kk) -> s16x8 {
    int r = wc * 64 + ni * 16 + l15;
    int slot = (kk * 4 + lg) ^ (r & 7);
    return *(const s16x8*)(lds + B2OFF(buf) + r * 128 + slot * 16);
  };

  f32x4 acc[2][2][4];
#pragma unroll
  for (int p = 0; p < 2; ++p)
#pragma unroll
    for (int mi = 0; mi < 2; ++mi)
#pragma unroll
      for (int ni = 0; ni < 4; ++ni) acc[p][mi][ni] = fzero4();

  stage_half(A,  lda, m0,       0,  AOFF(0, 0));
  stage_half(Bw, K,   n0,       0,  B2OFF(0));
  stage_half(A,  lda, m0 + 128, 0,  AOFF(0, 1));
  stage_half(A,  lda, m0,       64, AOFF(1, 0));
  stage_half(Bw, K,   n0,       64, B2OFF(1));
  asm volatile("s_waitcnt vmcnt(4)" ::: "memory");
  __builtin_amdgcn_s_barrier();

  int cur = 0;
  for (int t = 0; t < NT; ++t, cur ^= 1) {
    const int nxt = cur ^ 1;
    s16x8 af[2][2], b0f[4][2];
#pragma unroll
    for (int mi = 0; mi < 2; ++mi) {
      af[mi][0] = rdA(cur, 0, mi, 0);
      af[mi][1] = rdA(cur, 0, mi, 1);
    }
#pragma unroll
    for (int ni = 0; ni < 4; ++ni) {
      b0f[ni][0] = rdB(cur, ni, 0);
      b0f[ni][1] = rdB(cur, ni, 1);
    }
    if (t + 1 < NT) stage_half(A, lda, m0 + 128, (t + 1) * 64, AOFF(nxt, 1));
    __builtin_amdgcn_s_barrier();
    asm volatile("s_waitcnt lgkmcnt(0)" ::: "memory");
    __builtin_amdgcn_s_setprio(1);
    PH_MFMA(0, b0f);
    __builtin_amdgcn_s_setprio(0);
    __builtin_amdgcn_s_barrier();
#pragma unroll
    for (int mi = 0; mi < 2; ++mi) {
      af[mi][0] = rdA(cur, 1, mi, 0);
      af[mi][1] = rdA(cur, 1, mi, 1);
    }
    if (t + 2 < NT) {
      stage_half(A,  lda, m0, (t + 2) * 64, AOFF(cur, 0));
      stage_half(Bw, K,   n0, (t + 2) * 64, B2OFF(cur));
    }
    __builtin_amdgcn_s_barrier();
    asm volatile("s_waitcnt lgkmcnt(0)" ::: "memory");
    __builtin_amdgcn_s_setprio(1);
    PH_MFMA(1, b0f);
    __builtin_amdgcn_s_setprio(0);
    if (t < NT - 2) asm volatile("s_waitcnt vmcnt(4)" ::: "memory");
    else            asm volatile("s_waitcnt vmcnt(0)" ::: "memory");
    __builtin_amdgcn_s_barrier();
  }

#pragma unroll
  for (int p = 0; p < 2; ++p)
#pragma unroll
    for (int mi = 0; mi < 2; ++mi)
#pragma unroll
      for (int ni = 0; ni < 4; ++ni)
#pragma unroll
        for (int j = 0; j < 4; ++j) {
          int row_g = m0 + p * 128 + wr * 32 + mi * 16 + lg * 4 + j;
          int col_g = n0 + wc * 64 + ni * 16 + l15;
          float v = acc[p][mi][ni][j];
          size_t o = (size_t)row_g * ldc + col_g;
          float gv = g[row_g];
          dout[o] = gv * v + (1.f - gv) * bf2f(omem[o]);
        }
}

// ---------------- gather-GEMM: k_sh/v_sh for the 8 selected rows per (b,h) ----------------
__global__ __launch_bounds__(256) void gsel_kernel(const unsigned short* __restrict__ mem_bf,
                                                   const unsigned short* __restrict__ wkv,
                                                   const int* __restrict__ idx,
                                                   float* __restrict__ kshp,
                                                   float* __restrict__ vshp) {
  __shared__ __align__(16) unsigned short selA[16][2056];
  __shared__ int selL[8];
  const int tid = threadIdx.x;
  const int h = blockIdx.x, b = blockIdx.y;
  const int kvh = h >> 1;
  if (tid < 8) selL[tid] = idx[(b * H_ + h) * KSEL + tid];
  __syncthreads();
#pragma unroll
  for (int it = 0; it < 8; ++it) {
    int i = it * 256 + tid;
    int r = i >> 8, c8 = i & 255;
    *(s16x8*)&selA[r][c8 * 8] =
        *(const s16x8*)(mem_bf + ((size_t)(b * NMEM + selL[r])) * D_ + c8 * 8);
  }
  {
    s16x8 z = {0, 0, 0, 0, 0, 0, 0, 0};
#pragma unroll
    for (int it = 0; it < 8; ++it) {
      int i = it * 256 + tid;
      int r = 8 + (i >> 8), c8 = i & 255;
      *(s16x8*)&selA[r][c8 * 8] = z;
    }
  }
  __syncthreads();
  const int w = tid >> 6, lane = tid & 63;
  const int l15 = lane & 15, lg = lane >> 4;
  f32x4 acc[4];
#pragma unroll
  for (int ni = 0; ni < 4; ++ni) acc[ni] = fzero4();
  const unsigned short* brow[4];
#pragma unroll
  for (int ni = 0; ni < 4; ++ni) {
    int col = w * 64 + ni * 16 + l15;
    brow[ni] = (col < 128)
        ? (wkv + (size_t)(kvh * DH_ + col) * D_)
        : (wkv + (size_t)(KV_ * DH_ + kvh * DH_ + (col - 128)) * D_);
  }
  for (int kt = 0; kt < D_ / 32; ++kt) {
    s16x8 af = *(const s16x8*)&selA[l15][kt * 32 + lg * 8];
#pragma unroll
    for (int ni = 0; ni < 4; ++ni) {
      s16x8 bf_ = *(const s16x8*)(brow[ni] + kt * 32 + lg * 8);
      acc[ni] = __builtin_amdgcn_mfma_f32_16x16x32_bf16(af, bf_, acc[ni], 0, 0, 0);
    }
  }
#pragma unroll
  for (int ni = 0; ni < 4; ++ni)
#pragma unroll
    for (int j = 0; j < 4; ++j) {
      int row = lg * 4 + j;
      int col = w * 64 + ni * 16 + l15;
      if (row < 8) {
        float* outp = (col < 128 ? kshp : vshp) +
                      ((size_t)(b * H_ + h) * KSEL + row) * DH_ + (col & 127);
        *outp = acc[ni][j];
      }
    }
}

// ---------------- in-place pairwise RoPE (bf16) ----------------
__global__ __launch_bounds__(256) void rope_ip_kernel(unsigned short* __restrict__ buf,
                                                      const float* __restrict__ cosp,
                                                      const float* __restrict__ sinp,
                                                      int logp, int stride, int nthreads) {
  int i = blockIdx.x * 256 + threadIdx.x;
  if (i >= nthreads) return;
  int pp = i * 8;
  int row = pp >> logp;
  int p0 = pp & ((1 << logp) - 1);
  int blk = p0 >> 6, dd0 = p0 & 63;
  int b = row >> 11, t = row & 2047;
  const float* cb = cosp + ((size_t)b * T_ + t) * DH_;
  const float* sb = sinp + ((size_t)b * T_ + t) * DH_;
  unsigned short* p1 = buf + (size_t)row * stride + blk * 128 + dd0;
  s16x8 a = *(s16x8*)p1;
  s16x8 b8 = *(s16x8*)(p1 + 64);
  s16x8 o1, o2;
#pragma unroll
  for (int e = 0; e < 8; ++e) {
    float c1 = cb[dd0 + e], s1 = sb[dd0 + e];
    float c2 = cb[dd0 + 64 + e], s2 = sb[dd0 + 64 + e];
    float x1 = bf2f((unsigned short)a[e]), x2 = bf2f((unsigned short)b8[e]);
    o1[e] = (short)f2bf(x1 * c1 - x2 * s1);
    o2[e] = (short)f2bf(x2 * c2 + x1 * s2);
  }
  *(s16x8*)p1 = o1;
  *(s16x8*)(p1 + 64) = o2;
}

// ---------------- C/S partials (8 t-splits, 32-d tiles) ----------------
__global__ __launch_bounds__(256) void cs_kernel(const float* __restrict__ hs,
                                                 const float* __restrict__ cosp,
                                                 const float* __restrict__ sinp,
                                                 float* __restrict__ Cp, float* __restrict__ Sp) {
  __shared__ __align__(16) float hsL[32][128];
  __shared__ __align__(16) float csL[32][32];
  __shared__ __align__(16) float snL[32][32];
  const int tid = threadIdx.x;
  const int j0 = blockIdx.x * 128, d0 = blockIdx.y * 32;
  const int b = blockIdx.z >> 3, sp = blockIdx.z & 7;
  const int dq = (tid & 7) * 4;
  const int jq = (tid >> 3) * 4;
  float4 aC[4], aS[4];
#pragma unroll
  for (int a = 0; a < 4; ++a) {
    aC[a] = make_float4(0.f, 0.f, 0.f, 0.f);
    aS[a] = make_float4(0.f, 0.f, 0.f, 0.f);
  }
  const int csrow = tid >> 3, csc4 = tid & 7;
  for (int tile = 0; tile < 8; ++tile) {
    int t0 = sp * 256 + tile * 32;
    const float4* hs4 = (const float4*)(hs + ((size_t)b * T_ + t0) * D_ + j0);
#pragma unroll
    for (int r = 0; r < 4; ++r) {
      int i = tid + r * 256;
      int row = i >> 5, c4 = i & 31;
      *(float4*)&hsL[row][c4 * 4] = hs4[(size_t)row * (D_ / 4) + c4];
    }
    const float4* cp4 = (const float4*)(cosp + ((size_t)b * T_ + t0) * DH_ + d0);
    const float4* sp4 = (const float4*)(sinp + ((size_t)b * T_ + t0) * DH_ + d0);
    *(float4*)&csL[csrow][csc4 * 4] = cp4[(size_t)csrow * (DH_ / 4) + csc4];
    *(float4*)&snL[csrow][csc4 * 4] = sp4[(size_t)csrow * (DH_ / 4) + csc4];
    __syncthreads();
#pragma unroll 8
    for (int tt = 0; tt < 32; ++tt) {
      float4 cv = *(const float4*)&csL[tt][dq];
      float4 sv = *(const float4*)&snL[tt][dq];
      float4 hv = *(const float4*)&hsL[tt][jq];
      float ca[4] = {cv.x, cv.y, cv.z, cv.w};
      float sa[4] = {sv.x, sv.y, sv.z, sv.w};
#pragma unroll
      for (int a = 0; a < 4; ++a) {
        aC[a].x += ca[a] * hv.x; aC[a].y += ca[a] * hv.y;
        aC[a].z += ca[a] * hv.z; aC[a].w += ca[a] * hv.w;
        aS[a].x += sa[a] * hv.x; aS[a].y += sa[a] * hv.y;
        aS[a].z += sa[a] * hv.z; aS[a].w += sa[a] * hv.w;
      }
    }
    __syncthreads();
  }
#pragma unroll
  for (int a = 0; a < 4; ++a) {
    size_t o = ((size_t)(sp * B_ + b) * DH_ + d0 + dq + a) * D_ + j0 + jq;
    *(float4*)&Cp[o] = aC[a];
    *(float4*)&Sp[o] = aS[a];
  }
}

// ---------------- fused reduce(8 partials) + q_chunk (bitwise == old reduce->qchunk) ----------------
__global__ __launch_bounds__(256) void rqc_kernel(const float* __restrict__ Wq,
                                                  const float4* __restrict__ Cp,
                                                  const float4* __restrict__ Sp,
                                                  float* __restrict__ qc) {
  __shared__ float CrL[2048];
  __shared__ float SrL[2048];
  const int bd = blockIdx.x;          // b*128 + d
  const int b = bd >> 7, d = bd & 127;
  const int tid = threadIdx.x;
  const int str4 = (B_ * DH_ * D_) / 4;   // per-partial float4 stride
  const size_t base4 = ((size_t)b * DH_ + d) * (D_ / 4);
#pragma unroll
  for (int r = 0; r < 2; ++r) {
    int i4 = tid + r * 256;            // [0,512)
    float4 c = Cp[base4 + i4];
    float4 s = Sp[base4 + i4];
#pragma unroll
    for (int p = 1; p < 8; ++p) {
      float4 cp = Cp[base4 + (size_t)p * str4 + i4];
      float4 sq = Sp[base4 + (size_t)p * str4 + i4];
      c.x += cp.x; c.y += cp.y; c.z += cp.z; c.w += cp.w;
      s.x += sq.x; s.y += sq.y; s.z += sq.z; s.w += sq.w;
    }
    *(float4*)&CrL[i4 * 4] = c;
    *(float4*)&SrL[i4 * 4] = s;
  }
  __syncthreads();
  const int w = tid >> 6, lane = tid & 63;
  const int dp = (d < 64) ? d + 64 : d - 64;
  const float sgn = (d < 64) ? -1.f : 1.f;
#pragma unroll
  for (int hh = 0; hh < 4; ++hh) {
    int h = w + hh * 4;
    const float* w1 = Wq + (size_t)(h * DH_ + d) * D_;
    const float* w2 = Wq + (size_t)(h * DH_ + dp) * D_;
    float a1 = 0.f, a2 = 0.f;
    for (int j = lane; j < D_; j += 64) { a1 += w1[j] * CrL[j]; a2 += w2[j] * SrL[j]; }
#pragma unroll
    for (int off = 1; off < 64; off <<= 1) { a1 += __shfl_xor(a1, off); a2 += __shfl_xor(a2, off); }
    if (lane == 0) qc[((size_t)b * H_ + h) * DH_ + d] = (a1 + sgn * a2) * (1.f / (float)T_);
  }
}

// ---------------- z[b,h,j] = sum_d qc[b,h,d] * Wk[kvh*128+d][j] ----------------
__global__ __launch_bounds__(256) void zk_kernel(const float* __restrict__ qc,
                                                 const float* __restrict__ Wk,
                                                 float* __restrict__ z) {
  int j = blockIdx.x * 256 + threadIdx.x;
  int h = blockIdx.y, b = blockIdx.z;
  int kvh = h >> 1;
  const float* qcl = qc + ((size_t)b * H_ + h) * DH_;
  const float* wb = Wk + (size_t)kvh * DH_ * D_ + j;
  float acc = 0.f;
#pragma unroll 8
  for (int d = 0; d < 128; ++d) acc += qcl[d] * wb[(size_t)d * D_];
  z[((size_t)b * H_ + h) * D_ + j] = acc;
}

// ---------------- sim[b,h,n] = kScale * z[b,h,:] . mem[b,n,:] ----------------
__global__ __launch_bounds__(256) void sim_kernel(const float* __restrict__ z,
                                                  const float* __restrict__ mem,
                                                  float* __restrict__ sim) {
  __shared__ float4 mL[16 * 512];
  int tid = threadIdx.x;
  int n0 = blockIdx.x * 16, b = blockIdx.y;
  const float4* mem4 = (const float4*)(mem + (size_t)b * NMEM * D_);
#pragma unroll
  for (int c = 0; c < 32; ++c) {
    int i = tid + c * 256;
    int r = i >> 9, j4 = i & 511;
    mL[r * 512 + (j4 ^ (r & 7))] = mem4[(size_t)(n0 + r) * 512 + j4];
  }
  __syncthreads();
  int h = tid >> 4, n = tid & 15;
  const float4* zr = (const float4*)(z + ((size_t)b * H_ + h) * D_);
  float acc = 0.f;
  for (int j4 = 0; j4 < 512; ++j4) {
    float4 zz = zr[j4];
    float4 mm = mL[n * 512 + (j4 ^ (n & 7))];
    acc += zz.x * mm.x + zz.y * mm.y + zz.z * mm.z + zz.w * mm.w;
  }
  sim[((size_t)b * H_ + h) * NMEM + n0 + n] = acc * kScale;
}

// ---------------- top-8 per (b,h) ----------------
__global__ __launch_bounds__(256) void topk_kernel(const float* __restrict__ sim,
                                                   int* __restrict__ idx) {
  __shared__ float sL[1024];
  __shared__ float rv[256];
  __shared__ int ri[256];
  int tid = threadIdx.x;
  int h = blockIdx.x, b = blockIdx.y;
  const float* sp = sim + ((size_t)b * H_ + h) * NMEM;
#pragma unroll
  for (int r = 0; r < 4; ++r) sL[tid + r * 256] = sp[tid + r * 256];
  __syncthreads();
  for (int kk = 0; kk < 8; ++kk) {
    float bv = -INFINITY; int bi = 0x7fffffff;
#pragma unroll
    for (int r = 0; r < 4; ++r) {
      int i = tid + r * 256;
      float v = sL[i];
      if (v > bv || (v == bv && i < bi)) { bv = v; bi = i; }
    }
    rv[tid] = bv; ri[tid] = bi;
    __syncthreads();
    for (int s = 128; s > 0; s >>= 1) {
      if (tid < s) {
        float v2 = rv[tid + s]; int i2 = ri[tid + s];
        if (v2 > rv[tid] || (v2 == rv[tid] && i2 < ri[tid])) { rv[tid] = v2; ri[tid] = i2; }
      }
      __syncthreads();
    }
    if (tid == 0) { idx[((size_t)b * H_ + h) * KSEL + kk] = ri[0]; sL[ri[0]] = -INFINITY; }
    __syncthreads();
  }
}

// ---------------- memory-branch attention (fp32 ksh/vsh) ----------------
__global__ __launch_bounds__(256) void memattn_kernel(const unsigned short* __restrict__ qbf,
                                                      const float* __restrict__ ksh,
                                                      const float* __restrict__ vsh,
                                                      unsigned short* __restrict__ omem) {
  __shared__ float kl[8][128];
  __shared__ float vl[8][128];
  int tid = threadIdx.x;
  int b = blockIdx.z, h = blockIdx.y, t = blockIdx.x * 256 + tid;
  const float* ks = ksh + ((size_t)b * H_ + h) * KSEL * DH_;
  const float* vs = vsh + ((size_t)b * H_ + h) * KSEL * DH_;
#pragma unroll
  for (int r = 0; r < 4; ++r) {
    int i = tid + r * 256;
    ((float*)kl)[i] = ks[i];
    ((float*)vl)[i] = vs[i];
  }
  __syncthreads();
  float sc[8] = {0.f,0.f,0.f,0.f,0.f,0.f,0.f,0.f};
  const unsigned short* qr = qbf + (size_t)(b * T_ + t) * QKVSTR + h * DH_;
  for (int c = 0; c < 4; ++c) {
    const s16x8* qp = (const s16x8*)(qr + c * 32);
#pragma unroll
    for (int u = 0; u < 4; ++u) {
      s16x8 q8 = qp[u];
#pragma unroll
      for (int e = 0; e < 8; ++e) {
        float qv = bf2f((unsigned short)q8[e]);
        int d = c * 32 + u * 8 + e;
#pragma unroll
        for (int kk = 0; kk < 8; ++kk) sc[kk] += qv * kl[kk][d];
      }
    }
  }
  float sm[8], mx = -INFINITY;
#pragma unroll
  for (int kk = 0; kk < 8; ++kk) { sm[kk] = sc[kk] * kScale; mx = fmaxf(mx, sm[kk]); }
  float sum = 0.f;
#pragma unroll
  for (int kk = 0; kk < 8; ++kk) { sm[kk] = __expf(sm[kk] - mx); sum += sm[kk]; }
  float inv = 1.f / sum;
#pragma unroll
  for (int kk = 0; kk < 8; ++kk) sm[kk] *= inv;
  unsigned short* orow = omem + (size_t)(b * T_ + t) * D_ + h * DH_;
  for (int d = 0; d < 128; d += 4) {
    float o0 = 0.f, o1 = 0.f, o2 = 0.f, o3 = 0.f;
#pragma unroll
    for (int kk = 0; kk < 8; ++kk) {
      float w = sm[kk];
      o0 += w * vl[kk][d + 0];
      o1 += w * vl[kk][d + 1];
      o2 += w * vl[kk][d + 2];
      o3 += w * vl[kk][d + 3];
    }
    uint2 pk;
    pk.x = (unsigned)f2bf(o0) | ((unsigned)f2bf(o1) << 16);
    pk.y = (unsigned)f2bf(o2) | ((unsigned)f2bf(o3) << 16);
    *(uint2*)(orow + d) = pk;
  }
}

// ---------------- gate ----------------
__global__ __launch_bounds__(256) void gate_kernel(const float* __restrict__ hs,
                                                   const float* __restrict__ Wg,
                                                   const float* __restrict__ bg,
                                                   float* __restrict__ g) {
  int gid = blockIdx.x * 256 + threadIdx.x;
  int row = gid >> 6, lane = gid & 63;
  const float4* hr = (const float4*)(hs + (size_t)row * D_);
  const float4* wg4 = (const float4*)Wg;
  float acc = 0.f;
#pragma unroll
  for (int it = 0; it < 8; ++it) {
    float4 hv = hr[lane + it * 64], wv = wg4[lane + it * 64];
    acc += hv.x * wv.x + hv.y * wv.y + hv.z * wv.z + hv.w * wv.w;
  }
#pragma unroll
  for (int off = 1; off < 64; off <<= 1) acc += __shfl_xor(acc, off);
  if (lane == 0) g[row] = 1.f / (1.f + __expf(-(acc + bg[0])));
}

// ---------------- local sliding-window attention (LDS staging; per-wave tile skip) ----------------
__global__ __launch_bounds__(256) void localattn_kernel(const unsigned short* __restrict__ qbf,
                                                        const unsigned short* __restrict__ kbf,
                                                        const unsigned short* __restrict__ vbf,
                                                        unsigned short* __restrict__ olocal) {
  __shared__ __align__(16) unsigned short kL[2][32][128];
  __shared__ __align__(16) unsigned short vL[2][128][32];
  __shared__ __align__(16) unsigned short pl[4][16][40];
  const int tid = threadIdx.x;
  const int w = tid >> 6, lane = tid & 63;
  const int tb = blockIdx.x * 64;
  const int h = blockIdx.y, b = blockIdx.z;
  const int kvh = h >> 1;
  const int t0 = tb + w * 16;
  const int l15 = lane & 15, lg = lane >> 4;

  s16x8 qf[4];
  {
    const unsigned short* qb = qbf + ((size_t)(b * T_ + t0 + l15) * QKVSTR) + h * DH_ + lg * 8;
#pragma unroll
    for (int kb = 0; kb < 4; ++kb) qf[kb] = *(const s16x8*)(qb + kb * 32);
  }
  f32x4 of[8];
#pragma unroll
  for (int nb = 0; nb < 8; ++nb) of[nb] = fzero4();
  float m_r[4] = {-INFINITY, -INFINITY, -INFINITY, -INFINITY};
  float l_r[4] = {0.f, 0.f, 0.f, 0.f};

  int sstart = tb - (WWIN - 1);
  if (sstart < 0) sstart = 0;
  sstart &= ~31;
  const int slast = tb + 63;
  int wlow = t0 - (WWIN - 1);
  if (wlow < 0) wlow = 0;
  wlow &= ~31;
  const int whigh = t0 + 15;

  const int vk = tid & 15, vcg = tid >> 4;
  auto STAGE = [&](int buf, int s0) {
#pragma unroll
    for (int ld = 0; ld < 2; ++ld) {
      int s = ld * 256 + tid;
      int r = s >> 4, cs = s & 15;
      int cg = cs ^ (r & 7);
      const unsigned short* src = kbf + (size_t)(b * T_ + s0 + r) * QKVSTR + kvh * DH_ + cg * 8;
      __builtin_amdgcn_global_load_lds((const __attribute__((address_space(1))) void*)src,
          (__attribute__((address_space(3))) void*)((char*)&kL[buf][0][0] + ld * 4096 + w * 1024), 16, 0, 0);
    }
    {
      int r0 = 2 * vk;
      const unsigned short* vs = vbf + (size_t)(b * T_ + s0 + r0) * QKVSTR + kvh * DH_ + vcg * 8;
      s16x8 va = *(const s16x8*)vs;
      s16x8 vb2 = *(const s16x8*)(vs + QKVSTR);
      int q = vk >> 2;
      int colbase = 2 * (vk & 3);
#pragma unroll
      for (int e = 0; e < 8; ++e) {
        int c = vcg * 8 + e;
        int blk = q ^ ((c >> 2) & 3);
        unsigned int val = (unsigned int)(unsigned short)va[e] |
                           ((unsigned int)(unsigned short)vb2[e] << 16);
        *(unsigned int*)&vL[buf][c][blk * 8 + colbase] = val;
      }
    }
  };

  STAGE(0, sstart);
  int buf = 0;
  const int vp = (l15 >> 2) & 3;
  for (int s0 = sstart; s0 <= slast; s0 += 32, buf ^= 1) {
    __syncthreads();
    if (s0 + 32 <= slast) STAGE(buf ^ 1, s0 + 32);

    if (s0 >= wlow && s0 <= whigh) {
      f32x4 sc[2];
      sc[0] = fzero4(); sc[1] = fzero4();
#pragma unroll
      for (int cb = 0; cb < 2; ++cb) {
#pragma unroll
        for (int kb = 0; kb < 4; ++kb) {
          int r = cb * 16 + l15;
          int c = kb * 4 + lg;
          s16x8 kf = *(const s16x8*)((char*)&kL[buf][0][0] + r * 256 + ((c ^ (r & 7)) * 16));
          sc[cb] = __builtin_amdgcn_mfma_f32_16x16x32_bf16(qf[kb], kf, sc[cb], 0, 0, 0);
        }
      }
      float pv[2][4];
#pragma unroll
      for (int j = 0; j < 4; ++j) {
        int t = t0 + lg * 4 + j;
        int s_a = s0 + l15, s_b = s_a + 16;
        float va = sc[0][j] * kScale;
        float vb = sc[1][j] * kScale;
        va = (s_a <= t && s_a + (WWIN - 1) >= t) ? va : -INFINITY;
        vb = (s_b <= t && s_b + (WWIN - 1) >= t) ? vb : -INFINITY;
        float mx = fmaxf(va, vb);
#pragma unroll
        for (int off = 1; off < 16; off <<= 1) mx = fmaxf(mx, __shfl_xor(mx, off));
        float mn = fmaxf(m_r[j], mx);
        float alpha, pa, pb;
        if (mn == -INFINITY) { alpha = 1.f; pa = 0.f; pb = 0.f; }
        else {
          alpha = __expf(m_r[j] - mn);
          pa = __expf(va - mn);
          pb = __expf(vb - mn);
        }
        m_r[j] = mn;
        float rs = pa + pb;
#pragma unroll
        for (int off = 1; off < 16; off <<= 1) rs += __shfl_xor(rs, off);
        l_r[j] = l_r[j] * alpha + rs;
#pragma unroll
        for (int nb = 0; nb < 8; ++nb) of[nb][j] *= alpha;
        pv[0][j] = pa; pv[1][j] = pb;
      }
#pragma unroll
      for (int cb = 0; cb < 2; ++cb)
#pragma unroll
        for (int j = 0; j < 4; ++j)
          pl[w][lg * 4 + j][cb * 16 + l15] = f2bf(pv[cb][j]);
      asm volatile("s_waitcnt lgkmcnt(0)" ::: "memory");
      __builtin_amdgcn_sched_barrier(0);
      s16x8 pa8 = *(const s16x8*)&pl[w][l15][lg * 8];
#pragma unroll
      for (int nb = 0; nb < 8; ++nb) {
        int c = nb * 16 + l15;
        s16x8 vf = *(const s16x8*)&vL[buf][c][(lg ^ vp) * 8];
        of[nb] = __builtin_amdgcn_mfma_f32_16x16x32_bf16(pa8, vf, of[nb], 0, 0, 0);
      }
    }
  }

  float inv[4];
#pragma unroll
  for (int j = 0; j < 4; ++j) inv[j] = 1.f / l_r[j];
#pragma unroll
  for (int nb = 0; nb < 8; ++nb)
#pragma unroll
    for (int j = 0; j < 4; ++j) {
      int t = t0 + lg * 4 + j;
      olocal[(size_t)(b * T_ + t) * QKVSTR + h * DH_ + nb * 16 + l15] = f2bf(of[nb][j] * inv[j]);
    }
}

// ---------------- host launcher ----------------
extern "C" void kernel_launch(void* const* d_in, const int* in_sizes, int n_in,
                              void* d_out, int out_size, void* d_ws, size_t ws_size,
                              hipStream_t stream) {
  const float* hs   = (const float*)d_in[0];
  const float* cosp = (const float*)d_in[1];
  const float* sinp = (const float*)d_in[2];
  const float* mem  = (const float*)d_in[3];
  const float* Wq   = (const float*)d_in[4];
  const float* Wk   = (const float*)d_in[5];
  const float* Wv   = (const float*)d_in[6];
  const float* Wo   = (const float*)d_in[7];
  const float* Wg   = (const float*)d_in[8];
  const float* bg   = (const float*)d_in[9];
  float* out = (float*)d_out;

  char* p = (char*)d_ws;
  auto alloc = [&](size_t bytes) { char* r = p; p += (bytes + 255) & ~(size_t)255; return r; };
  float* qc     = (float*)alloc((size_t)B_ * H_ * DH_ * 4);
  float* gbuf   = (float*)alloc((size_t)BT * 4);
  float* zbuf   = (float*)alloc((size_t)B_ * H_ * D_ * 4);
  float* simbuf = (float*)alloc((size_t)B_ * H_ * NMEM * 4);
  int*   idxbuf = (int*)alloc((size_t)B_ * H_ * KSEL * 4);
  float* ksh    = (float*)alloc((size_t)B_ * H_ * KSEL * DH_ * 4);
  float* vsh    = (float*)alloc((size_t)B_ * H_ * KSEL * DH_ * 4);
  unsigned short* hs_bf   = (unsigned short*)alloc((size_t)BT * D_ * 2);       // -> o_mem bf16 later
  unsigned short* qkv_raw = (unsigned short*)alloc((size_t)BT * QKVSTR * 2);   // q|k|v merged; q -> o_local in place
  unsigned short* wbig    = (unsigned short*)alloc((size_t)2 * D_ * D_ * 2);   // Wq|Wk|Wv stack
  unsigned short* mem_bf  = (unsigned short*)alloc((size_t)B_ * NMEM * D_ * 2);
  unsigned short* wo_bf   = (unsigned short*)alloc((size_t)D_ * D_ * 2);       // Wo bf16

  // C/S partials live in d_out (33.5 MB; fully rewritten by final GEMM)
  float* Cp = (float*)d_out;
  float* Sp = Cp + (size_t)8 * B_ * DH_ * D_;
  unsigned short* omem_bf = hs_bf;

  // 1) one merged conversion launch (hs, Wq, Wk, Wv, mem, Wo)
  conv6_kernel<<<24576, 256, 0, stream>>>(hs, Wq, Wk, Wv, mem, Wo, hs_bf, wbig, mem_bf, wo_bf);

  // 2) merged QKV projection (256^2 8-phase)
  gemm256<0><<<dim3(QKVSTR / 256, BT / 256), 512, 0, stream>>>(hs_bf, wbig, QKVSTR, D_, D_, QKVSTR, qkv_raw, nullptr, nullptr, nullptr);

  // 3) in-place RoPE
  rope_ip_kernel<<<(BT * D_ / 16 + 255) / 256, 256, 0, stream>>>(qkv_raw, cosp, sinp, 10, QKVSTR, BT * D_ / 16);
  rope_ip_kernel<<<(BT * KV_ * DH_ / 16 + 255) / 256, 256, 0, stream>>>(qkv_raw + D_, cosp, sinp, 9, QKVSTR, BT * KV_ * DH_ / 16);

  // 4) exact-fp32 selection path (fused reduce+qchunk)
  cs_kernel<<<dim3(D_ / 128, DH_ / 32, B_ * 8), 256, 0, stream>>>(hs, cosp, sinp, Cp, Sp);
  rqc_kernel<<<B_ * DH_, 256, 0, stream>>>(Wq, (const float4*)Cp, (const float4*)Sp, qc);
  zk_kernel<<<dim3(D_ / 256, H_, B_), 256, 0, stream>>>(qc, Wk, zbuf);
  sim_kernel<<<dim3(NMEM / 16, B_), 256, 0, stream>>>(zbuf, mem, simbuf);
  topk_kernel<<<dim3(H_, B_), 256, 0, stream>>>(simbuf, idxbuf);

  // 5) gather-GEMM for selected K/V rows, then memory-branch attention -> o_mem bf16
  gsel_kernel<<<dim3(H_, B_), 256, 0, stream>>>(mem_bf, wbig + (size_t)D_ * D_, idxbuf, ksh, vsh);
  memattn_kernel<<<dim3(T_ / 256, H_, B_), 256, 0, stream>>>(qkv_raw, ksh, vsh, omem_bf);

  // 6) gate
  gate_kernel<<<BT / 4, 256, 0, stream>>>(hs, Wg, bg, gbuf);

  // 7) local sliding-window attention (writes o_local in place over q section)
  localattn_kernel<<<dim3(T_ / 64, H_, B_), 256, 0, stream>>>(qkv_raw, qkv_raw + D_, qkv_raw + D_ + KV_ * DH_, qkv_raw);

  // 8) Wo projection + final combine (256x128 tile -> 256 blocks, full machine)
  gemm256n<<<dim3(D_ / 128, BT / 256), 512, 0, stream>>>(qkv_raw, wo_bf, D_, D_, QKVSTR, D_, gbuf, omem_bf, out);
}

// Round 19
// 400.191 us; speedup vs baseline: 1.0513x; 1.0513x over previous
//
#include <hip/hip_runtime.h>
#include <stdint.h>

#define B_   2
#define T_   2048
#define D_   2048
#define H_   16
#define KV_  8
#define DH_  128
#define NMEM 1024
#define WWIN 256
#define KSEL 8
#define BT   (B_*T_)
#define QKVSTR 4096   // merged qkv row stride (elements)

__constant__ const float kScale = 0.08838834764831845f; // DH^-0.5

typedef __attribute__((ext_vector_type(8))) short s16x8;
typedef __attribute__((ext_vector_type(4))) float f32x4;

__device__ inline unsigned short f2bf(float f) {
  union { float f; unsigned int u; } c; c.f = f;
  unsigned int u = c.u;
  unsigned int r = u + 0x7fffu + ((u >> 16) & 1u);
  return (unsigned short)(r >> 16);
}
__device__ inline float bf2f(unsigned short v) {
  union { unsigned int u; float f; } c; c.u = ((unsigned int)v) << 16;
  return c.f;
}
__device__ inline f32x4 fzero4() { f32x4 v; v[0]=0.f; v[1]=0.f; v[2]=0.f; v[3]=0.f; return v; }

// ---------------- fp32 -> bf16 conversion (float4 wide) ----------------
__global__ __launch_bounds__(256) void conv_kernel(const float* __restrict__ src,
                                                   unsigned short* __restrict__ dst, int n) {
  int i = blockIdx.x * 256 + threadIdx.x;
  if (i * 4 >= n) return;
  float4 v = ((const float4*)src)[i];
  uint2 o;
  o.x = (unsigned)f2bf(v.x) | ((unsigned)f2bf(v.y) << 16);
  o.y = (unsigned)f2bf(v.z) | ((unsigned)f2bf(v.w) << 16);
  ((uint2*)dst)[i] = o;
}

// ================= 256x256 8-phase GEMM (T2+T3+T4+T5) =================
#define AOFF(buf, half) ((buf)*32768 + (half)*16384)
#define BOFF(buf, half) (65536 + (buf)*32768 + (half)*16384)

#define PH_MFMA(P, BF) \
  { \
    _Pragma("unroll") \
    for (int mi = 0; mi < 2; ++mi) { \
      _Pragma("unroll") \
      for (int ni = 0; ni < 4; ++ni) { \
        acc[P][mi][ni] = __builtin_amdgcn_mfma_f32_16x16x32_bf16(af[mi][0], BF[ni][0], acc[P][mi][ni], 0, 0, 0); \
        acc[P][mi][ni] = __builtin_amdgcn_mfma_f32_16x16x32_bf16(af[mi][1], BF[ni][1], acc[P][mi][ni], 0, 0, 0); \
      } \
    } \
  }

template<int MODE>
__global__ __launch_bounds__(512, 2) void gemm256(const unsigned short* __restrict__ A,
                                                  const unsigned short* __restrict__ Bw,
                                                  int N, int K, int lda, int ldc,
                                                  unsigned short* __restrict__ Cb,
                                                  const float* __restrict__ g,
                                                  const unsigned short* __restrict__ omem,
                                                  float* __restrict__ dout) {
  __shared__ __align__(16) char lds[131072];
  const int tid = threadIdx.x;
  const int wv = tid >> 6, lane = tid & 63;
  const int l15 = lane & 15, lg = lane >> 4;
  const int wr = wv >> 1, wc = wv & 1;
  const int gx = gridDim.x;
  const int nwg = gx * gridDim.y;
  const int flat = blockIdx.y * gx + blockIdx.x;
  const int chunk = nwg >> 3;
  const int wg = (flat & 7) * chunk + (flat >> 3);
  const int bx = wg % gx, by = wg / gx;
  const int m0 = by * 256, n0 = bx * 256;
  const int NT = K >> 6;

  auto stage_half = [&](const unsigned short* base, int stride, int row0, int koff, int ldsoff) {
#pragma unroll
    for (int ld = 0; ld < 2; ++ld) {
      int s = ld * 512 + tid;
      int row = s >> 3, cs = s & 7;
      int cg = cs ^ (row & 7);
      const unsigned short* src = base + (size_t)(row0 + row) * stride + koff + cg * 8;
      __builtin_amdgcn_global_load_lds((const __attribute__((address_space(1))) void*)src,
          (__attribute__((address_space(3))) void*)(lds + ldsoff + ld * 8192 + wv * 1024), 16, 0, 0);
    }
  };
  auto rdA = [&](int buf, int half, int mi, int kk) -> s16x8 {
    int r = wr * 32 + mi * 16 + l15;
    int slot = (kk * 4 + lg) ^ (r & 7);
    return *(const s16x8*)(lds + AOFF(buf, half) + r * 128 + slot * 16);
  };
  auto rdB = [&](int buf, int half, int ni, int kk) -> s16x8 {
    int r = wc * 64 + ni * 16 + l15;
    int slot = (kk * 4 + lg) ^ (r & 7);
    return *(const s16x8*)(lds + BOFF(buf, half) + r * 128 + slot * 16);
  };

  f32x4 acc[4][2][4];
#pragma unroll
  for (int p = 0; p < 4; ++p)
#pragma unroll
    for (int mi = 0; mi < 2; ++mi)
#pragma unroll
      for (int ni = 0; ni < 4; ++ni) acc[p][mi][ni] = fzero4();

  stage_half(A,  lda, m0,       0,  AOFF(0, 0));
  stage_half(Bw, K,   n0,       0,  BOFF(0, 0));
  stage_half(A,  lda, m0 + 128, 0,  AOFF(0, 1));
  stage_half(Bw, K,   n0 + 128, 0,  BOFF(0, 1));
  stage_half(A,  lda, m0,       64, AOFF(1, 0));
  stage_half(Bw, K,   n0,       64, BOFF(1, 0));
  stage_half(A,  lda, m0 + 128, 64, AOFF(1, 1));
  asm volatile("s_waitcnt vmcnt(6)" ::: "memory");
  __builtin_amdgcn_s_barrier();

  int cur = 0;
  for (int t = 0; t < NT; ++t, cur ^= 1) {
    const int nxt = cur ^ 1;
    s16x8 af[2][2], b0f[4][2], b1f[4][2];
#pragma unroll
    for (int mi = 0; mi < 2; ++mi) {
      af[mi][0] = rdA(cur, 0, mi, 0);
      af[mi][1] = rdA(cur, 0, mi, 1);
    }
#pragma unroll
    for (int ni = 0; ni < 4; ++ni) {
      b0f[ni][0] = rdB(cur, 0, ni, 0);
      b0f[ni][1] = rdB(cur, 0, ni, 1);
    }
    if (t + 1 < NT) stage_half(Bw, K, n0 + 128, (t + 1) * 64, BOFF(nxt, 1));
    __builtin_amdgcn_s_barrier();
    asm volatile("s_waitcnt lgkmcnt(0)" ::: "memory");
    __builtin_amdgcn_s_setprio(1);
    PH_MFMA(0, b0f);
    __builtin_amdgcn_s_setprio(0);
    __builtin_amdgcn_s_barrier();
#pragma unroll
    for (int ni = 0; ni < 4; ++ni) {
      b1f[ni][0] = rdB(cur, 1, ni, 0);
      b1f[ni][1] = rdB(cur, 1, ni, 1);
    }
    if (t + 2 < NT) stage_half(A, lda, m0, (t + 2) * 64, AOFF(cur, 0));
    __builtin_amdgcn_s_barrier();
    asm volatile("s_waitcnt lgkmcnt(0)" ::: "memory");
    __builtin_amdgcn_s_setprio(1);
    PH_MFMA(1, b1f);
    __builtin_amdgcn_s_setprio(0);
    __builtin_amdgcn_s_barrier();
#pragma unroll
    for (int mi = 0; mi < 2; ++mi) {
      af[mi][0] = rdA(cur, 1, mi, 0);
      af[mi][1] = rdA(cur, 1, mi, 1);
    }
    if (t + 2 < NT) stage_half(Bw, K, n0, (t + 2) * 64, BOFF(cur, 0));
    __builtin_amdgcn_s_barrier();
    asm volatile("s_waitcnt lgkmcnt(0)" ::: "memory");
    __builtin_amdgcn_s_setprio(1);
    PH_MFMA(2, b0f);
    __builtin_amdgcn_s_setprio(0);
    __builtin_amdgcn_s_barrier();
    if (t + 2 < NT) stage_half(A, lda, m0 + 128, (t + 2) * 64, AOFF(cur, 1));
    __builtin_amdgcn_s_barrier();
    asm volatile("s_waitcnt lgkmcnt(0)" ::: "memory");
    __builtin_amdgcn_s_setprio(1);
    PH_MFMA(3, b1f);
    __builtin_amdgcn_s_setprio(0);
    if (t < NT - 2) asm volatile("s_waitcnt vmcnt(6)" ::: "memory");
    else            asm volatile("s_waitcnt vmcnt(0)" ::: "memory");
    __builtin_amdgcn_s_barrier();
  }

#pragma unroll
  for (int p = 0; p < 4; ++p)
#pragma unroll
    for (int mi = 0; mi < 2; ++mi)
#pragma unroll
      for (int ni = 0; ni < 4; ++ni)
#pragma unroll
        for (int j = 0; j < 4; ++j) {
          int row_g = m0 + (p >> 1) * 128 + wr * 32 + mi * 16 + lg * 4 + j;
          int col_g = n0 + (p & 1) * 128 + wc * 64 + ni * 16 + l15;
          float v = acc[p][mi][ni][j];
          size_t o = (size_t)row_g * ldc + col_g;
          if constexpr (MODE == 0) {
            Cb[o] = f2bf(v);
          } else {
            float gv = g[row_g];
            dout[o] = gv * v + (1.f - gv) * bf2f(omem[o]);
          }
        }
}

// ================= 256x128 2-phase GEMM (full-machine grid for N=2048) =================
#define B2OFF(buf) (65536 + (buf)*16384)

__global__ __launch_bounds__(512, 2) void gemm256n(const unsigned short* __restrict__ A,
                                                   const unsigned short* __restrict__ Bw,
                                                   int N, int K, int lda, int ldc,
                                                   const float* __restrict__ g,
                                                   const unsigned short* __restrict__ omem,
                                                   float* __restrict__ dout) {
  __shared__ __align__(16) char lds[98304];
  const int tid = threadIdx.x;
  const int wv = tid >> 6, lane = tid & 63;
  const int l15 = lane & 15, lg = lane >> 4;
  const int wr = wv >> 1, wc = wv & 1;
  const int gx = gridDim.x;
  const int nwg = gx * gridDim.y;
  const int flat = blockIdx.y * gx + blockIdx.x;
  const int chunk = nwg >> 3;
  const int wg = (flat & 7) * chunk + (flat >> 3);
  const int bx = wg % gx, by = wg / gx;
  const int m0 = by * 256, n0 = bx * 128;
  const int NT = K >> 6;

  auto stage_half = [&](const unsigned short* base, int stride, int row0, int koff, int ldsoff) {
#pragma unroll
    for (int ld = 0; ld < 2; ++ld) {
      int s = ld * 512 + tid;
      int row = s >> 3, cs = s & 7;
      int cg = cs ^ (row & 7);
      const unsigned short* src = base + (size_t)(row0 + row) * stride + koff + cg * 8;
      __builtin_amdgcn_global_load_lds((const __attribute__((address_space(1))) void*)src,
          (__attribute__((address_space(3))) void*)(lds + ldsoff + ld * 8192 + wv * 1024), 16, 0, 0);
    }
  };
  auto rdA = [&](int buf, int half, int mi, int kk) -> s16x8 {
    int r = wr * 32 + mi * 16 + l15;
    int slot = (kk * 4 + lg) ^ (r & 7);
    return *(const s16x8*)(lds + AOFF(buf, half) + r * 128 + slot * 16);
  };
  auto rdB = [&](int buf, int ni, int kk) -> s16x8 {
    int r = wc * 64 + ni * 16 + l15;
    int slot = (kk * 4 + lg) ^ (r & 7);
    return *(const s16x8*)(lds + B2OFF(buf) + r * 128 + slot * 16);
  };

  f32x4 acc[2][2][4];
#pragma unroll
  for (int p = 0; p < 2; ++p)
#pragma unroll
    for (int mi = 0; mi < 2; ++mi)
#pragma unroll
      for (int ni = 0; ni < 4; ++ni) acc[p][mi][ni] = fzero4();

  stage_half(A,  lda, m0,       0,  AOFF(0, 0));
  stage_half(Bw, K,   n0,       0,  B2OFF(0));
  stage_half(A,  lda, m0 + 128, 0,  AOFF(0, 1));
  stage_half(A,  lda, m0,       64, AOFF(1, 0));
  stage_half(Bw, K,   n0,       64, B2OFF(1));
  asm volatile("s_waitcnt vmcnt(4)" ::: "memory");
  __builtin_amdgcn_s_barrier();

  int cur = 0;
  for (int t = 0; t < NT; ++t, cur ^= 1) {
    const int nxt = cur ^ 1;
    s16x8 af[2][2], b0f[4][2];
#pragma unroll
    for (int mi = 0; mi < 2; ++mi) {
      af[mi][0] = rdA(cur, 0, mi, 0);
      af[mi][1] = rdA(cur, 0, mi, 1);
    }
#pragma unroll
    for (int ni = 0; ni < 4; ++ni) {
      b0f[ni][0] = rdB(cur, ni, 0);
      b0f[ni][1] = rdB(cur, ni, 1);
    }
    if (t + 1 < NT) stage_half(A, lda, m0 + 128, (t + 1) * 64, AOFF(nxt, 1));
    __builtin_amdgcn_s_barrier();
    asm volatile("s_waitcnt lgkmcnt(0)" ::: "memory");
    __builtin_amdgcn_s_setprio(1);
    PH_MFMA(0, b0f);
    __builtin_amdgcn_s_setprio(0);
    __builtin_amdgcn_s_barrier();
#pragma unroll
    for (int mi = 0; mi < 2; ++mi) {
      af[mi][0] = rdA(cur, 1, mi, 0);
      af[mi][1] = rdA(cur, 1, mi, 1);
    }
    if (t + 2 < NT) {
      stage_half(A,  lda, m0, (t + 2) * 64, AOFF(cur, 0));
      stage_half(Bw, K,   n0, (t + 2) * 64, B2OFF(cur));
    }
    __builtin_amdgcn_s_barrier();
    asm volatile("s_waitcnt lgkmcnt(0)" ::: "memory");
    __builtin_amdgcn_s_setprio(1);
    PH_MFMA(1, b0f);
    __builtin_amdgcn_s_setprio(0);
    if (t < NT - 2) asm volatile("s_waitcnt vmcnt(4)" ::: "memory");
    else            asm volatile("s_waitcnt vmcnt(0)" ::: "memory");
    __builtin_amdgcn_s_barrier();
  }

#pragma unroll
  for (int p = 0; p < 2; ++p)
#pragma unroll
    for (int mi = 0; mi < 2; ++mi)
#pragma unroll
      for (int ni = 0; ni < 4; ++ni)
#pragma unroll
        for (int j = 0; j < 4; ++j) {
          int row_g = m0 + p * 128 + wr * 32 + mi * 16 + lg * 4 + j;
          int col_g = n0 + wc * 64 + ni * 16 + l15;
          float v = acc[p][mi][ni][j];
          size_t o = (size_t)row_g * ldc + col_g;
          float gv = g[row_g];
          dout[o] = gv * v + (1.f - gv) * bf2f(omem[o]);
        }
}

// ---------------- gather-GEMM: k_sh/v_sh for the 8 selected rows per (b,h) ----------------
__global__ __launch_bounds__(256) void gsel_kernel(const unsigned short* __restrict__ mem_bf,
                                                   const unsigned short* __restrict__ wkv,
                                                   const int* __restrict__ idx,
                                                   float* __restrict__ kshp,
                                                   float* __restrict__ vshp) {
  __shared__ __align__(16) unsigned short selA[16][2056];
  __shared__ int selL[8];
  const int tid = threadIdx.x;
  const int h = blockIdx.x, b = blockIdx.y;
  const int kvh = h >> 1;
  if (tid < 8) selL[tid] = idx[(b * H_ + h) * KSEL + tid];
  __syncthreads();
#pragma unroll
  for (int it = 0; it < 8; ++it) {
    int i = it * 256 + tid;
    int r = i >> 8, c8 = i & 255;
    *(s16x8*)&selA[r][c8 * 8] =
        *(const s16x8*)(mem_bf + ((size_t)(b * NMEM + selL[r])) * D_ + c8 * 8);
  }
  {
    s16x8 z = {0, 0, 0, 0, 0, 0, 0, 0};
#pragma unroll
    for (int it = 0; it < 8; ++it) {
      int i = it * 256 + tid;
      int r = 8 + (i >> 8), c8 = i & 255;
      *(s16x8*)&selA[r][c8 * 8] = z;
    }
  }
  __syncthreads();
  const int w = tid >> 6, lane = tid & 63;
  const int l15 = lane & 15, lg = lane >> 4;
  f32x4 acc[4];
#pragma unroll
  for (int ni = 0; ni < 4; ++ni) acc[ni] = fzero4();
  const unsigned short* brow[4];
#pragma unroll
  for (int ni = 0; ni < 4; ++ni) {
    int col = w * 64 + ni * 16 + l15;
    brow[ni] = (col < 128)
        ? (wkv + (size_t)(kvh * DH_ + col) * D_)
        : (wkv + (size_t)(KV_ * DH_ + kvh * DH_ + (col - 128)) * D_);
  }
  for (int kt = 0; kt < D_ / 32; ++kt) {
    s16x8 af = *(const s16x8*)&selA[l15][kt * 32 + lg * 8];
#pragma unroll
    for (int ni = 0; ni < 4; ++ni) {
      s16x8 bf_ = *(const s16x8*)(brow[ni] + kt * 32 + lg * 8);
      acc[ni] = __builtin_amdgcn_mfma_f32_16x16x32_bf16(af, bf_, acc[ni], 0, 0, 0);
    }
  }
#pragma unroll
  for (int ni = 0; ni < 4; ++ni)
#pragma unroll
    for (int j = 0; j < 4; ++j) {
      int row = lg * 4 + j;
      int col = w * 64 + ni * 16 + l15;
      if (row < 8) {
        float* outp = (col < 128 ? kshp : vshp) +
                      ((size_t)(b * H_ + h) * KSEL + row) * DH_ + (col & 127);
        *outp = acc[ni][j];
      }
    }
}

// ---------------- merged in-place pairwise RoPE (q + k sections, one launch) ----------------
__global__ __launch_bounds__(256) void rope_ip2_kernel(unsigned short* __restrict__ qkv,
                                                       const float* __restrict__ cosp,
                                                       const float* __restrict__ sinp) {
  int blk = blockIdx.x, tid = threadIdx.x;
  unsigned short* buf;
  int logp, i;
  if (blk < 2048) { buf = qkv;      logp = 10; i = blk * 256 + tid; }          // q section
  else            { buf = qkv + D_; logp = 9;  i = (blk - 2048) * 256 + tid; } // k section
  int pp = i * 8;
  int row = pp >> logp;
  int p0 = pp & ((1 << logp) - 1);
  int blk2 = p0 >> 6, dd0 = p0 & 63;
  int b = row >> 11, t = row & 2047;
  const float* cb = cosp + ((size_t)b * T_ + t) * DH_;
  const float* sb = sinp + ((size_t)b * T_ + t) * DH_;
  unsigned short* p1 = buf + (size_t)row * QKVSTR + blk2 * 128 + dd0;
  s16x8 a = *(s16x8*)p1;
  s16x8 b8 = *(s16x8*)(p1 + 64);
  s16x8 o1, o2;
#pragma unroll
  for (int e = 0; e < 8; ++e) {
    float c1 = cb[dd0 + e], s1 = sb[dd0 + e];
    float c2 = cb[dd0 + 64 + e], s2 = sb[dd0 + 64 + e];
    float x1 = bf2f((unsigned short)a[e]), x2 = bf2f((unsigned short)b8[e]);
    o1[e] = (short)f2bf(x1 * c1 - x2 * s1);
    o2[e] = (short)f2bf(x2 * c2 + x1 * s2);
  }
  *(s16x8*)p1 = o1;
  *(s16x8*)(p1 + 64) = o2;
}

// ---------------- C/S partials (8 t-splits, 32-d tiles) ----------------
__global__ __launch_bounds__(256) void cs_kernel(const float* __restrict__ hs,
                                                 const float* __restrict__ cosp,
                                                 const float* __restrict__ sinp,
                                                 float* __restrict__ Cp, float* __restrict__ Sp) {
  __shared__ __align__(16) float hsL[32][128];
  __shared__ __align__(16) float csL[32][32];
  __shared__ __align__(16) float snL[32][32];
  const int tid = threadIdx.x;
  const int j0 = blockIdx.x * 128, d0 = blockIdx.y * 32;
  const int b = blockIdx.z >> 3, sp = blockIdx.z & 7;
  const int dq = (tid & 7) * 4;
  const int jq = (tid >> 3) * 4;
  float4 aC[4], aS[4];
#pragma unroll
  for (int a = 0; a < 4; ++a) {
    aC[a] = make_float4(0.f, 0.f, 0.f, 0.f);
    aS[a] = make_float4(0.f, 0.f, 0.f, 0.f);
  }
  const int csrow = tid >> 3, csc4 = tid & 7;
  for (int tile = 0; tile < 8; ++tile) {
    int t0 = sp * 256 + tile * 32;
    const float4* hs4 = (const float4*)(hs + ((size_t)b * T_ + t0) * D_ + j0);
#pragma unroll
    for (int r = 0; r < 4; ++r) {
      int i = tid + r * 256;
      int row = i >> 5, c4 = i & 31;
      *(float4*)&hsL[row][c4 * 4] = hs4[(size_t)row * (D_ / 4) + c4];
    }
    const float4* cp4 = (const float4*)(cosp + ((size_t)b * T_ + t0) * DH_ + d0);
    const float4* sp4 = (const float4*)(sinp + ((size_t)b * T_ + t0) * DH_ + d0);
    *(float4*)&csL[csrow][csc4 * 4] = cp4[(size_t)csrow * (DH_ / 4) + csc4];
    *(float4*)&snL[csrow][csc4 * 4] = sp4[(size_t)csrow * (DH_ / 4) + csc4];
    __syncthreads();
#pragma unroll 8
    for (int tt = 0; tt < 32; ++tt) {
      float4 cv = *(const float4*)&csL[tt][dq];
      float4 sv = *(const float4*)&snL[tt][dq];
      float4 hv = *(const float4*)&hsL[tt][jq];
      float ca[4] = {cv.x, cv.y, cv.z, cv.w};
      float sa[4] = {sv.x, sv.y, sv.z, sv.w};
#pragma unroll
      for (int a = 0; a < 4; ++a) {
        aC[a].x += ca[a] * hv.x; aC[a].y += ca[a] * hv.y;
        aC[a].z += ca[a] * hv.z; aC[a].w += ca[a] * hv.w;
        aS[a].x += sa[a] * hv.x; aS[a].y += sa[a] * hv.y;
        aS[a].z += sa[a] * hv.z; aS[a].w += sa[a] * hv.w;
      }
    }
    __syncthreads();
  }
#pragma unroll
  for (int a = 0; a < 4; ++a) {
    size_t o = ((size_t)(sp * B_ + b) * DH_ + d0 + dq + a) * D_ + j0 + jq;
    *(float4*)&Cp[o] = aC[a];
    *(float4*)&Sp[o] = aS[a];
  }
}

// ---------------- reduce 8 partials -> Cr/Sr ----------------
__global__ __launch_bounds__(256) void reduce_cs_kernel(const float4* __restrict__ Cp,
                                                        const float4* __restrict__ Sp,
                                                        float4* __restrict__ Cr,
                                                        float4* __restrict__ Sr) {
  int i = blockIdx.x * 256 + threadIdx.x;
  const int str = (B_ * DH_ * D_) / 4;
  float4 c = Cp[i], s = Sp[i];
#pragma unroll
  for (int p = 1; p < 8; ++p) {
    float4 cp = Cp[i + (size_t)p * str], sq = Sp[i + (size_t)p * str];
    c.x += cp.x; c.y += cp.y; c.z += cp.z; c.w += cp.w;
    s.x += sq.x; s.y += sq.y; s.z += sq.z; s.w += sq.w;
  }
  Cr[i] = c; Sr[i] = s;
}

// ---------------- q_chunk[b,h,d] from reduced C/S (exact fp32) ----------------
__global__ __launch_bounds__(256) void qchunk_kernel(const float* __restrict__ Wq,
                                                     const float* __restrict__ Cr,
                                                     const float* __restrict__ Sr,
                                                     float* __restrict__ qc) {
  int gid = blockIdx.x * 256 + threadIdx.x;
  int wid = gid >> 6, lane = gid & 63;
  int b = wid >> 11, rem = wid & 2047;
  int h = rem >> 7, d = rem & 127;
  const float* w1 = Wq + (size_t)(h * DH_ + d) * D_;
  int dp = (d < 64) ? d + 64 : d - 64;
  float sgn = (d < 64) ? -1.f : 1.f;
  const float* w2 = Wq + (size_t)(h * DH_ + dp) * D_;
  const float* crow = Cr + ((size_t)b * DH_ + d) * D_;
  const float* srow = Sr + ((size_t)b * DH_ + d) * D_;
  float a1 = 0.f, a2 = 0.f;
  for (int j = lane; j < D_; j += 64) { a1 += w1[j] * crow[j]; a2 += w2[j] * srow[j]; }
#pragma unroll
  for (int off = 1; off < 64; off <<= 1) { a1 += __shfl_xor(a1, off); a2 += __shfl_xor(a2, off); }
  if (lane == 0) qc[wid] = (a1 + sgn * a2) * (1.f / (float)T_);
}

// ---------------- z[b,h,j] = sum_d qc[b,h,d] * Wk[kvh*128+d][j] ----------------
__global__ __launch_bounds__(256) void zk_kernel(const float* __restrict__ qc,
                                                 const float* __restrict__ Wk,
                                                 float* __restrict__ z) {
  int j = blockIdx.x * 256 + threadIdx.x;
  int h = blockIdx.y, b = blockIdx.z;
  int kvh = h >> 1;
  const float* qcl = qc + ((size_t)b * H_ + h) * DH_;
  const float* wb = Wk + (size_t)kvh * DH_ * D_ + j;
  float acc = 0.f;
#pragma unroll 8
  for (int d = 0; d < 128; ++d) acc += qcl[d] * wb[(size_t)d * D_];
  z[((size_t)b * H_ + h) * D_ + j] = acc;
}

// ---------------- sim[b,h,n] = kScale * z[b,h,:] . mem[b,n,:] ----------------
__global__ __launch_bounds__(256) void sim_kernel(const float* __restrict__ z,
                                                  const float* __restrict__ mem,
                                                  float* __restrict__ sim) {
  __shared__ float4 mL[16 * 512];
  int tid = threadIdx.x;
  int n0 = blockIdx.x * 16, b = blockIdx.y;
  const float4* mem4 = (const float4*)(mem + (size_t)b * NMEM * D_);
#pragma unroll
  for (int c = 0; c < 32; ++c) {
    int i = tid + c * 256;
    int r = i >> 9, j4 = i & 511;
    mL[r * 512 + (j4 ^ (r & 7))] = mem4[(size_t)(n0 + r) * 512 + j4];
  }
  __syncthreads();
  int h = tid >> 4, n = tid & 15;
  const float4* zr = (const float4*)(z + ((size_t)b * H_ + h) * D_);
  float acc = 0.f;
  for (int j4 = 0; j4 < 512; ++j4) {
    float4 zz = zr[j4];
    float4 mm = mL[n * 512 + (j4 ^ (n & 7))];
    acc += zz.x * mm.x + zz.y * mm.y + zz.z * mm.z + zz.w * mm.w;
  }
  sim[((size_t)b * H_ + h) * NMEM + n0 + n] = acc * kScale;
}

// ---------------- top-8 per (b,h) ----------------
__global__ __launch_bounds__(256) void topk_kernel(const float* __restrict__ sim,
                                                   int* __restrict__ idx) {
  __shared__ float sL[1024];
  __shared__ float rv[256];
  __shared__ int ri[256];
  int tid = threadIdx.x;
  int h = blockIdx.x, b = blockIdx.y;
  const float* sp = sim + ((size_t)b * H_ + h) * NMEM;
#pragma unroll
  for (int r = 0; r < 4; ++r) sL[tid + r * 256] = sp[tid + r * 256];
  __syncthreads();
  for (int kk = 0; kk < 8; ++kk) {
    float bv = -INFINITY; int bi = 0x7fffffff;
#pragma unroll
    for (int r = 0; r < 4; ++r) {
      int i = tid + r * 256;
      float v = sL[i];
      if (v > bv || (v == bv && i < bi)) { bv = v; bi = i; }
    }
    rv[tid] = bv; ri[tid] = bi;
    __syncthreads();
    for (int s = 128; s > 0; s >>= 1) {
      if (tid < s) {
        float v2 = rv[tid + s]; int i2 = ri[tid + s];
        if (v2 > rv[tid] || (v2 == rv[tid] && i2 < ri[tid])) { rv[tid] = v2; ri[tid] = i2; }
      }
      __syncthreads();
    }
    if (tid == 0) { idx[((size_t)b * H_ + h) * KSEL + kk] = ri[0]; sL[ri[0]] = -INFINITY; }
    __syncthreads();
  }
}

// ---------------- memory-branch attention (fp32 ksh/vsh) ----------------
__global__ __launch_bounds__(256) void memattn_kernel(const unsigned short* __restrict__ qbf,
                                                      const float* __restrict__ ksh,
                                                      const float* __restrict__ vsh,
                                                      unsigned short* __restrict__ omem) {
  __shared__ float kl[8][128];
  __shared__ float vl[8][128];
  int tid = threadIdx.x;
  int b = blockIdx.z, h = blockIdx.y, t = blockIdx.x * 256 + tid;
  const float* ks = ksh + ((size_t)b * H_ + h) * KSEL * DH_;
  const float* vs = vsh + ((size_t)b * H_ + h) * KSEL * DH_;
#pragma unroll
  for (int r = 0; r < 4; ++r) {
    int i = tid + r * 256;
    ((float*)kl)[i] = ks[i];
    ((float*)vl)[i] = vs[i];
  }
  __syncthreads();
  float sc[8] = {0.f,0.f,0.f,0.f,0.f,0.f,0.f,0.f};
  const unsigned short* qr = qbf + (size_t)(b * T_ + t) * QKVSTR + h * DH_;
  for (int c = 0; c < 4; ++c) {
    const s16x8* qp = (const s16x8*)(qr + c * 32);
#pragma unroll
    for (int u = 0; u < 4; ++u) {
      s16x8 q8 = qp[u];
#pragma unroll
      for (int e = 0; e < 8; ++e) {
        float qv = bf2f((unsigned short)q8[e]);
        int d = c * 32 + u * 8 + e;
#pragma unroll
        for (int kk = 0; kk < 8; ++kk) sc[kk] += qv * kl[kk][d];
      }
    }
  }
  float sm[8], mx = -INFINITY;
#pragma unroll
  for (int kk = 0; kk < 8; ++kk) { sm[kk] = sc[kk] * kScale; mx = fmaxf(mx, sm[kk]); }
  float sum = 0.f;
#pragma unroll
  for (int kk = 0; kk < 8; ++kk) { sm[kk] = __expf(sm[kk] - mx); sum += sm[kk]; }
  float inv = 1.f / sum;
#pragma unroll
  for (int kk = 0; kk < 8; ++kk) sm[kk] *= inv;
  unsigned short* orow = omem + (size_t)(b * T_ + t) * D_ + h * DH_;
  for (int d = 0; d < 128; d += 4) {
    float o0 = 0.f, o1 = 0.f, o2 = 0.f, o3 = 0.f;
#pragma unroll
    for (int kk = 0; kk < 8; ++kk) {
      float w = sm[kk];
      o0 += w * vl[kk][d + 0];
      o1 += w * vl[kk][d + 1];
      o2 += w * vl[kk][d + 2];
      o3 += w * vl[kk][d + 3];
    }
    uint2 pk;
    pk.x = (unsigned)f2bf(o0) | ((unsigned)f2bf(o1) << 16);
    pk.y = (unsigned)f2bf(o2) | ((unsigned)f2bf(o3) << 16);
    *(uint2*)(orow + d) = pk;
  }
}

// ---------------- gate ----------------
__global__ __launch_bounds__(256) void gate_kernel(const float* __restrict__ hs,
                                                   const float* __restrict__ Wg,
                                                   const float* __restrict__ bg,
                                                   float* __restrict__ g) {
  int gid = blockIdx.x * 256 + threadIdx.x;
  int row = gid >> 6, lane = gid & 63;
  const float4* hr = (const float4*)(hs + (size_t)row * D_);
  const float4* wg4 = (const float4*)Wg;
  float acc = 0.f;
#pragma unroll
  for (int it = 0; it < 8; ++it) {
    float4 hv = hr[lane + it * 64], wv = wg4[lane + it * 64];
    acc += hv.x * wv.x + hv.y * wv.y + hv.z * wv.z + hv.w * wv.w;
  }
#pragma unroll
  for (int off = 1; off < 64; off <<= 1) acc += __shfl_xor(acc, off);
  if (lane == 0) g[row] = 1.f / (1.f + __expf(-(acc + bg[0])));
}

// ---------------- local sliding-window attention (LDS staging; per-wave tile skip) ----------------
__global__ __launch_bounds__(256) void localattn_kernel(const unsigned short* __restrict__ qbf,
                                                        const unsigned short* __restrict__ kbf,
                                                        const unsigned short* __restrict__ vbf,
                                                        unsigned short* __restrict__ olocal) {
  __shared__ __align__(16) unsigned short kL[2][32][128];
  __shared__ __align__(16) unsigned short vL[2][128][32];
  __shared__ __align__(16) unsigned short pl[4][16][40];
  const int tid = threadIdx.x;
  const int w = tid >> 6, lane = tid & 63;
  const int tb = blockIdx.x * 64;
  const int h = blockIdx.y, b = blockIdx.z;
  const int kvh = h >> 1;
  const int t0 = tb + w * 16;
  const int l15 = lane & 15, lg = lane >> 4;

  s16x8 qf[4];
  {
    const unsigned short* qb = qbf + ((size_t)(b * T_ + t0 + l15) * QKVSTR) + h * DH_ + lg * 8;
#pragma unroll
    for (int kb = 0; kb < 4; ++kb) qf[kb] = *(const s16x8*)(qb + kb * 32);
  }
  f32x4 of[8];
#pragma unroll
  for (int nb = 0; nb < 8; ++nb) of[nb] = fzero4();
  float m_r[4] = {-INFINITY, -INFINITY, -INFINITY, -INFINITY};
  float l_r[4] = {0.f, 0.f, 0.f, 0.f};

  int sstart = tb - (WWIN - 1);
  if (sstart < 0) sstart = 0;
  sstart &= ~31;
  const int slast = tb + 63;
  int wlow = t0 - (WWIN - 1);
  if (wlow < 0) wlow = 0;
  wlow &= ~31;
  const int whigh = t0 + 15;

  const int vk = tid & 15, vcg = tid >> 4;
  auto STAGE = [&](int buf, int s0) {
#pragma unroll
    for (int ld = 0; ld < 2; ++ld) {
      int s = ld * 256 + tid;
      int r = s >> 4, cs = s & 15;
      int cg = cs ^ (r & 7);
      const unsigned short* src = kbf + (size_t)(b * T_ + s0 + r) * QKVSTR + kvh * DH_ + cg * 8;
      __builtin_amdgcn_global_load_lds((const __attribute__((address_space(1))) void*)src,
          (__attribute__((address_space(3))) void*)((char*)&kL[buf][0][0] + ld * 4096 + w * 1024), 16, 0, 0);
    }
    {
      int r0 = 2 * vk;
      const unsigned short* vs = vbf + (size_t)(b * T_ + s0 + r0) * QKVSTR + kvh * DH_ + vcg * 8;
      s16x8 va = *(const s16x8*)vs;
      s16x8 vb2 = *(const s16x8*)(vs + QKVSTR);
      int q = vk >> 2;
      int colbase = 2 * (vk & 3);
#pragma unroll
      for (int e = 0; e < 8; ++e) {
        int c = vcg * 8 + e;
        int blk = q ^ ((c >> 2) & 3);
        unsigned int val = (unsigned int)(unsigned short)va[e] |
                           ((unsigned int)(unsigned short)vb2[e] << 16);
        *(unsigned int*)&vL[buf][c][blk * 8 + colbase] = val;
      }
    }
  };

  STAGE(0, sstart);
  int buf = 0;
  const int vp = (l15 >> 2) & 3;
  for (int s0 = sstart; s0 <= slast; s0 += 32, buf ^= 1) {
    __syncthreads();
    if (s0 + 32 <= slast) STAGE(buf ^ 1, s0 + 32);

    if (s0 >= wlow && s0 <= whigh) {
      f32x4 sc[2];
      sc[0] = fzero4(); sc[1] = fzero4();
#pragma unroll
      for (int cb = 0; cb < 2; ++cb) {
#pragma unroll
        for (int kb = 0; kb < 4; ++kb) {
          int r = cb * 16 + l15;
          int c = kb * 4 + lg;
          s16x8 kf = *(const s16x8*)((char*)&kL[buf][0][0] + r * 256 + ((c ^ (r & 7)) * 16));
          sc[cb] = __builtin_amdgcn_mfma_f32_16x16x32_bf16(qf[kb], kf, sc[cb], 0, 0, 0);
        }
      }
      float pv[2][4];
#pragma unroll
      for (int j = 0; j < 4; ++j) {
        int t = t0 + lg * 4 + j;
        int s_a = s0 + l15, s_b = s_a + 16;
        float va = sc[0][j] * kScale;
        float vb = sc[1][j] * kScale;
        va = (s_a <= t && s_a + (WWIN - 1) >= t) ? va : -INFINITY;
        vb = (s_b <= t && s_b + (WWIN - 1) >= t) ? vb : -INFINITY;
        float mx = fmaxf(va, vb);
#pragma unroll
        for (int off = 1; off < 16; off <<= 1) mx = fmaxf(mx, __shfl_xor(mx, off));
        float mn = fmaxf(m_r[j], mx);
        float alpha, pa, pb;
        if (mn == -INFINITY) { alpha = 1.f; pa = 0.f; pb = 0.f; }
        else {
          alpha = __expf(m_r[j] - mn);
          pa = __expf(va - mn);
          pb = __expf(vb - mn);
        }
        m_r[j] = mn;
        float rs = pa + pb;
#pragma unroll
        for (int off = 1; off < 16; off <<= 1) rs += __shfl_xor(rs, off);
        l_r[j] = l_r[j] * alpha + rs;
#pragma unroll
        for (int nb = 0; nb < 8; ++nb) of[nb][j] *= alpha;
        pv[0][j] = pa; pv[1][j] = pb;
      }
#pragma unroll
      for (int cb = 0; cb < 2; ++cb)
#pragma unroll
        for (int j = 0; j < 4; ++j)
          pl[w][lg * 4 + j][cb * 16 + l15] = f2bf(pv[cb][j]);
      asm volatile("s_waitcnt lgkmcnt(0)" ::: "memory");
      __builtin_amdgcn_sched_barrier(0);
      s16x8 pa8 = *(const s16x8*)&pl[w][l15][lg * 8];
#pragma unroll
      for (int nb = 0; nb < 8; ++nb) {
        int c = nb * 16 + l15;
        s16x8 vf = *(const s16x8*)&vL[buf][c][(lg ^ vp) * 8];
        of[nb] = __builtin_amdgcn_mfma_f32_16x16x32_bf16(pa8, vf, of[nb], 0, 0, 0);
      }
    }
  }

  float inv[4];
#pragma unroll
  for (int j = 0; j < 4; ++j) inv[j] = 1.f / l_r[j];
#pragma unroll
  for (int nb = 0; nb < 8; ++nb)
#pragma unroll
    for (int j = 0; j < 4; ++j) {
      int t = t0 + lg * 4 + j;
      olocal[(size_t)(b * T_ + t) * QKVSTR + h * DH_ + nb * 16 + l15] = f2bf(of[nb][j] * inv[j]);
    }
}

// ---------------- host launcher ----------------
extern "C" void kernel_launch(void* const* d_in, const int* in_sizes, int n_in,
                              void* d_out, int out_size, void* d_ws, size_t ws_size,
                              hipStream_t stream) {
  const float* hs   = (const float*)d_in[0];
  const float* cosp = (const float*)d_in[1];
  const float* sinp = (const float*)d_in[2];
  const float* mem  = (const float*)d_in[3];
  const float* Wq   = (const float*)d_in[4];
  const float* Wk   = (const float*)d_in[5];
  const float* Wv   = (const float*)d_in[6];
  const float* Wo   = (const float*)d_in[7];
  const float* Wg   = (const float*)d_in[8];
  const float* bg   = (const float*)d_in[9];
  float* out = (float*)d_out;

  char* p = (char*)d_ws;
  auto alloc = [&](size_t bytes) { char* r = p; p += (bytes + 255) & ~(size_t)255; return r; };
  float* qc     = (float*)alloc((size_t)B_ * H_ * DH_ * 4);
  float* gbuf   = (float*)alloc((size_t)BT * 4);
  float* zbuf   = (float*)alloc((size_t)B_ * H_ * D_ * 4);
  float* simbuf = (float*)alloc((size_t)B_ * H_ * NMEM * 4);
  int*   idxbuf = (int*)alloc((size_t)B_ * H_ * KSEL * 4);
  float* ksh    = (float*)alloc((size_t)B_ * H_ * KSEL * DH_ * 4);
  float* vsh    = (float*)alloc((size_t)B_ * H_ * KSEL * DH_ * 4);
  unsigned short* hs_bf   = (unsigned short*)alloc((size_t)BT * D_ * 2);       // -> o_mem bf16 later
  unsigned short* qkv_raw = (unsigned short*)alloc((size_t)BT * QKVSTR * 2);   // q|k|v merged; q -> o_local in place
  unsigned short* wbig    = (unsigned short*)alloc((size_t)2 * D_ * D_ * 2);   // Wq|Wk|Wv stack
  unsigned short* mem_bf  = (unsigned short*)alloc((size_t)B_ * NMEM * D_ * 2);
  float* crsr             = (float*)alloc((size_t)2 * B_ * DH_ * D_ * 4);      // Cr|Sr

  // C/S partials live in d_out (33.5 MB; fully rewritten by final GEMM)
  float* Cp = (float*)d_out;
  float* Sp = Cp + (size_t)8 * B_ * DH_ * D_;
  float* Cr = crsr;
  float* Sr = Cr + (size_t)B_ * DH_ * D_;
  unsigned short* omem_bf = hs_bf;

  // 1) conversions + merged QKV projection (256^2 8-phase)
  conv_kernel<<<(BT * D_ / 4 + 255) / 256, 256, 0, stream>>>(hs, hs_bf, BT * D_);
  conv_kernel<<<(D_ * D_ / 4 + 255) / 256, 256, 0, stream>>>(Wq, wbig, D_ * D_);
  conv_kernel<<<(KV_ * DH_ * D_ / 4 + 255) / 256, 256, 0, stream>>>(Wk, wbig + (size_t)D_ * D_, KV_ * DH_ * D_);
  conv_kernel<<<(KV_ * DH_ * D_ / 4 + 255) / 256, 256, 0, stream>>>(Wv, wbig + (size_t)D_ * D_ + (size_t)KV_ * DH_ * D_, KV_ * DH_ * D_);
  gemm256<0><<<dim3(QKVSTR / 256, BT / 256), 512, 0, stream>>>(hs_bf, wbig, QKVSTR, D_, D_, QKVSTR, qkv_raw, nullptr, nullptr, nullptr);
  conv_kernel<<<(B_ * NMEM * D_ / 4 + 255) / 256, 256, 0, stream>>>(mem, mem_bf, B_ * NMEM * D_);

  // 2) merged in-place RoPE (q + k sections, one launch)
  rope_ip2_kernel<<<3072, 256, 0, stream>>>(qkv_raw, cosp, sinp);

  // 3) exact-fp32 selection path
  cs_kernel<<<dim3(D_ / 128, DH_ / 32, B_ * 8), 256, 0, stream>>>(hs, cosp, sinp, Cp, Sp);
  reduce_cs_kernel<<<(B_ * DH_ * D_ / 4) / 256, 256, 0, stream>>>((const float4*)Cp, (const float4*)Sp, (float4*)Cr, (float4*)Sr);
  qchunk_kernel<<<(B_ * H_ * DH_) / 4, 256, 0, stream>>>(Wq, Cr, Sr, qc);
  zk_kernel<<<dim3(D_ / 256, H_, B_), 256, 0, stream>>>(qc, Wk, zbuf);
  sim_kernel<<<dim3(NMEM / 16, B_), 256, 0, stream>>>(zbuf, mem, simbuf);
  topk_kernel<<<dim3(H_, B_), 256, 0, stream>>>(simbuf, idxbuf);

  // 4) gather-GEMM for selected K/V rows, then memory-branch attention -> o_mem bf16
  gsel_kernel<<<dim3(H_, B_), 256, 0, stream>>>(mem_bf, wbig + (size_t)D_ * D_, idxbuf, ksh, vsh);
  memattn_kernel<<<dim3(T_ / 256, H_, B_), 256, 0, stream>>>(qkv_raw, ksh, vsh, omem_bf);

  // 5) gate
  gate_kernel<<<BT / 4, 256, 0, stream>>>(hs, Wg, bg, gbuf);

  // 6) local sliding-window attention (writes o_local in place over q section)
  localattn_kernel<<<dim3(T_ / 64, H_, B_), 256, 0, stream>>>(qkv_raw, qkv_raw + D_, qkv_raw + D_ + KV_ * DH_, qkv_raw);

  // 7) Wo projection + final combine (256x128 tile -> 256 blocks, full machine)
  conv_kernel<<<(D_ * D_ / 4 + 255) / 256, 256, 0, stream>>>(Wo, wbig, D_ * D_);
  gemm256n<<<dim3(D_ / 128, BT / 256), 512, 0, stream>>>(qkv_raw, wbig, D_, D_, QKVSTR, D_, gbuf, omem_bf, out);
}

// Round 20
// 386.623 us; speedup vs baseline: 1.0882x; 1.0351x over previous
//
#include <hip/hip_runtime.h>
#include <stdint.h>

#define B_   2
#define T_   2048
#define D_   2048
#define H_   16
#define KV_  8
#define DH_  128
#define NMEM 1024
#define WWIN 256
#define KSEL 8
#define BT   (B_*T_)
#define QKVSTR 4096   // merged qkv row stride (elements)

__constant__ const float kScale = 0.08838834764831845f; // DH^-0.5

typedef __attribute__((ext_vector_type(8))) short s16x8;
typedef __attribute__((ext_vector_type(4))) float f32x4;

__device__ inline unsigned short f2bf(float f) {
  union { float f; unsigned int u; } c; c.f = f;
  unsigned int u = c.u;
  unsigned int r = u + 0x7fffu + ((u >> 16) & 1u);
  return (unsigned short)(r >> 16);
}
__device__ inline float bf2f(unsigned short v) {
  union { unsigned int u; float f; } c; c.u = ((unsigned int)v) << 16;
  return c.f;
}
__device__ inline f32x4 fzero4() { f32x4 v; v[0]=0.f; v[1]=0.f; v[2]=0.f; v[3]=0.f; return v; }

// ---------------- fp32 -> bf16 conversion (float4 wide) ----------------
__global__ __launch_bounds__(256) void conv_kernel(const float* __restrict__ src,
                                                   unsigned short* __restrict__ dst, int n) {
  int i = blockIdx.x * 256 + threadIdx.x;
  if (i * 4 >= n) return;
  float4 v = ((const float4*)src)[i];
  uint2 o;
  o.x = (unsigned)f2bf(v.x) | ((unsigned)f2bf(v.y) << 16);
  o.y = (unsigned)f2bf(v.z) | ((unsigned)f2bf(v.w) << 16);
  ((uint2*)dst)[i] = o;
}

// ================= 256x256 8-phase GEMM (T2+T3+T4+T5) =================
#define AOFF(buf, half) ((buf)*32768 + (half)*16384)
#define BOFF(buf, half) (65536 + (buf)*32768 + (half)*16384)

#define PH_MFMA(P, BF) \
  { \
    _Pragma("unroll") \
    for (int mi = 0; mi < 2; ++mi) { \
      _Pragma("unroll") \
      for (int ni = 0; ni < 4; ++ni) { \
        acc[P][mi][ni] = __builtin_amdgcn_mfma_f32_16x16x32_bf16(af[mi][0], BF[ni][0], acc[P][mi][ni], 0, 0, 0); \
        acc[P][mi][ni] = __builtin_amdgcn_mfma_f32_16x16x32_bf16(af[mi][1], BF[ni][1], acc[P][mi][ni], 0, 0, 0); \
      } \
    } \
  }

template<int MODE>
__global__ __launch_bounds__(512, 2) void gemm256(const unsigned short* __restrict__ A,
                                                  const unsigned short* __restrict__ Bw,
                                                  int N, int K, int lda, int ldc,
                                                  unsigned short* __restrict__ Cb,
                                                  const float* __restrict__ g,
                                                  const unsigned short* __restrict__ omem,
                                                  float* __restrict__ dout) {
  __shared__ __align__(16) char lds[131072];
  const int tid = threadIdx.x;
  const int wv = tid >> 6, lane = tid & 63;
  const int l15 = lane & 15, lg = lane >> 4;
  const int wr = wv >> 1, wc = wv & 1;
  const int gx = gridDim.x;
  const int nwg = gx * gridDim.y;
  const int flat = blockIdx.y * gx + blockIdx.x;
  const int chunk = nwg >> 3;
  const int wg = (flat & 7) * chunk + (flat >> 3);
  const int bx = wg % gx, by = wg / gx;
  const int m0 = by * 256, n0 = bx * 256;
  const int NT = K >> 6;

  auto stage_half = [&](const unsigned short* base, int stride, int row0, int koff, int ldsoff) {
#pragma unroll
    for (int ld = 0; ld < 2; ++ld) {
      int s = ld * 512 + tid;
      int row = s >> 3, cs = s & 7;
      int cg = cs ^ (row & 7);
      const unsigned short* src = base + (size_t)(row0 + row) * stride + koff + cg * 8;
      __builtin_amdgcn_global_load_lds((const __attribute__((address_space(1))) void*)src,
          (__attribute__((address_space(3))) void*)(lds + ldsoff + ld * 8192 + wv * 1024), 16, 0, 0);
    }
  };
  auto rdA = [&](int buf, int half, int mi, int kk) -> s16x8 {
    int r = wr * 32 + mi * 16 + l15;
    int slot = (kk * 4 + lg) ^ (r & 7);
    return *(const s16x8*)(lds + AOFF(buf, half) + r * 128 + slot * 16);
  };
  auto rdB = [&](int buf, int half, int ni, int kk) -> s16x8 {
    int r = wc * 64 + ni * 16 + l15;
    int slot = (kk * 4 + lg) ^ (r & 7);
    return *(const s16x8*)(lds + BOFF(buf, half) + r * 128 + slot * 16);
  };

  f32x4 acc[4][2][4];
#pragma unroll
  for (int p = 0; p < 4; ++p)
#pragma unroll
    for (int mi = 0; mi < 2; ++mi)
#pragma unroll
      for (int ni = 0; ni < 4; ++ni) acc[p][mi][ni] = fzero4();

  stage_half(A,  lda, m0,       0,  AOFF(0, 0));
  stage_half(Bw, K,   n0,       0,  BOFF(0, 0));
  stage_half(A,  lda, m0 + 128, 0,  AOFF(0, 1));
  stage_half(Bw, K,   n0 + 128, 0,  BOFF(0, 1));
  stage_half(A,  lda, m0,       64, AOFF(1, 0));
  stage_half(Bw, K,   n0,       64, BOFF(1, 0));
  stage_half(A,  lda, m0 + 128, 64, AOFF(1, 1));
  asm volatile("s_waitcnt vmcnt(6)" ::: "memory");
  __builtin_amdgcn_s_barrier();

  int cur = 0;
  for (int t = 0; t < NT; ++t, cur ^= 1) {
    const int nxt = cur ^ 1;
    s16x8 af[2][2], b0f[4][2], b1f[4][2];
#pragma unroll
    for (int mi = 0; mi < 2; ++mi) {
      af[mi][0] = rdA(cur, 0, mi, 0);
      af[mi][1] = rdA(cur, 0, mi, 1);
    }
#pragma unroll
    for (int ni = 0; ni < 4; ++ni) {
      b0f[ni][0] = rdB(cur, 0, ni, 0);
      b0f[ni][1] = rdB(cur, 0, ni, 1);
    }
    if (t + 1 < NT) stage_half(Bw, K, n0 + 128, (t + 1) * 64, BOFF(nxt, 1));
    __builtin_amdgcn_s_barrier();
    asm volatile("s_waitcnt lgkmcnt(0)" ::: "memory");
    __builtin_amdgcn_s_setprio(1);
    PH_MFMA(0, b0f);
    __builtin_amdgcn_s_setprio(0);
    __builtin_amdgcn_s_barrier();
#pragma unroll
    for (int ni = 0; ni < 4; ++ni) {
      b1f[ni][0] = rdB(cur, 1, ni, 0);
      b1f[ni][1] = rdB(cur, 1, ni, 1);
    }
    if (t + 2 < NT) stage_half(A, lda, m0, (t + 2) * 64, AOFF(cur, 0));
    __builtin_amdgcn_s_barrier();
    asm volatile("s_waitcnt lgkmcnt(0)" ::: "memory");
    __builtin_amdgcn_s_setprio(1);
    PH_MFMA(1, b1f);
    __builtin_amdgcn_s_setprio(0);
    __builtin_amdgcn_s_barrier();
#pragma unroll
    for (int mi = 0; mi < 2; ++mi) {
      af[mi][0] = rdA(cur, 1, mi, 0);
      af[mi][1] = rdA(cur, 1, mi, 1);
    }
    if (t + 2 < NT) stage_half(Bw, K, n0, (t + 2) * 64, BOFF(cur, 0));
    __builtin_amdgcn_s_barrier();
    asm volatile("s_waitcnt lgkmcnt(0)" ::: "memory");
    __builtin_amdgcn_s_setprio(1);
    PH_MFMA(2, b0f);
    __builtin_amdgcn_s_setprio(0);
    __builtin_amdgcn_s_barrier();
    if (t + 2 < NT) stage_half(A, lda, m0 + 128, (t + 2) * 64, AOFF(cur, 1));
    __builtin_amdgcn_s_barrier();
    asm volatile("s_waitcnt lgkmcnt(0)" ::: "memory");
    __builtin_amdgcn_s_setprio(1);
    PH_MFMA(3, b1f);
    __builtin_amdgcn_s_setprio(0);
    if (t < NT - 2) asm volatile("s_waitcnt vmcnt(6)" ::: "memory");
    else            asm volatile("s_waitcnt vmcnt(0)" ::: "memory");
    __builtin_amdgcn_s_barrier();
  }

#pragma unroll
  for (int p = 0; p < 4; ++p)
#pragma unroll
    for (int mi = 0; mi < 2; ++mi)
#pragma unroll
      for (int ni = 0; ni < 4; ++ni)
#pragma unroll
        for (int j = 0; j < 4; ++j) {
          int row_g = m0 + (p >> 1) * 128 + wr * 32 + mi * 16 + lg * 4 + j;
          int col_g = n0 + (p & 1) * 128 + wc * 64 + ni * 16 + l15;
          float v = acc[p][mi][ni][j];
          size_t o = (size_t)row_g * ldc + col_g;
          if constexpr (MODE == 0) {
            Cb[o] = f2bf(v);
          } else {
            float gv = g[row_g];
            dout[o] = gv * v + (1.f - gv) * bf2f(omem[o]);
          }
        }
}

// ================= 256x128 2-phase GEMM (full-machine grid for N=2048) =================
#define B2OFF(buf) (65536 + (buf)*16384)

__global__ __launch_bounds__(512, 2) void gemm256n(const unsigned short* __restrict__ A,
                                                   const unsigned short* __restrict__ Bw,
                                                   int N, int K, int lda, int ldc,
                                                   const float* __restrict__ g,
                                                   const unsigned short* __restrict__ omem,
                                                   float* __restrict__ dout) {
  __shared__ __align__(16) char lds[98304];
  const int tid = threadIdx.x;
  const int wv = tid >> 6, lane = tid & 63;
  const int l15 = lane & 15, lg = lane >> 4;
  const int wr = wv >> 1, wc = wv & 1;
  const int gx = gridDim.x;
  const int nwg = gx * gridDim.y;
  const int flat = blockIdx.y * gx + blockIdx.x;
  const int chunk = nwg >> 3;
  const int wg = (flat & 7) * chunk + (flat >> 3);
  const int bx = wg % gx, by = wg / gx;
  const int m0 = by * 256, n0 = bx * 128;
  const int NT = K >> 6;

  auto stage_half = [&](const unsigned short* base, int stride, int row0, int koff, int ldsoff) {
#pragma unroll
    for (int ld = 0; ld < 2; ++ld) {
      int s = ld * 512 + tid;
      int row = s >> 3, cs = s & 7;
      int cg = cs ^ (row & 7);
      const unsigned short* src = base + (size_t)(row0 + row) * stride + koff + cg * 8;
      __builtin_amdgcn_global_load_lds((const __attribute__((address_space(1))) void*)src,
          (__attribute__((address_space(3))) void*)(lds + ldsoff + ld * 8192 + wv * 1024), 16, 0, 0);
    }
  };
  auto rdA = [&](int buf, int half, int mi, int kk) -> s16x8 {
    int r = wr * 32 + mi * 16 + l15;
    int slot = (kk * 4 + lg) ^ (r & 7);
    return *(const s16x8*)(lds + AOFF(buf, half) + r * 128 + slot * 16);
  };
  auto rdB = [&](int buf, int ni, int kk) -> s16x8 {
    int r = wc * 64 + ni * 16 + l15;
    int slot = (kk * 4 + lg) ^ (r & 7);
    return *(const s16x8*)(lds + B2OFF(buf) + r * 128 + slot * 16);
  };

  f32x4 acc[2][2][4];
#pragma unroll
  for (int p = 0; p < 2; ++p)
#pragma unroll
    for (int mi = 0; mi < 2; ++mi)
#pragma unroll
      for (int ni = 0; ni < 4; ++ni) acc[p][mi][ni] = fzero4();

  stage_half(A,  lda, m0,       0,  AOFF(0, 0));
  stage_half(Bw, K,   n0,       0,  B2OFF(0));
  stage_half(A,  lda, m0 + 128, 0,  AOFF(0, 1));
  stage_half(A,  lda, m0,       64, AOFF(1, 0));
  stage_half(Bw, K,   n0,       64, B2OFF(1));
  asm volatile("s_waitcnt vmcnt(4)" ::: "memory");
  __builtin_amdgcn_s_barrier();

  int cur = 0;
  for (int t = 0; t < NT; ++t, cur ^= 1) {
    const int nxt = cur ^ 1;
    s16x8 af[2][2], b0f[4][2];
#pragma unroll
    for (int mi = 0; mi < 2; ++mi) {
      af[mi][0] = rdA(cur, 0, mi, 0);
      af[mi][1] = rdA(cur, 0, mi, 1);
    }
#pragma unroll
    for (int ni = 0; ni < 4; ++ni) {
      b0f[ni][0] = rdB(cur, ni, 0);
      b0f[ni][1] = rdB(cur, ni, 1);
    }
    if (t + 1 < NT) stage_half(A, lda, m0 + 128, (t + 1) * 64, AOFF(nxt, 1));
    __builtin_amdgcn_s_barrier();
    asm volatile("s_waitcnt lgkmcnt(0)" ::: "memory");
    __builtin_amdgcn_s_setprio(1);
    PH_MFMA(0, b0f);
    __builtin_amdgcn_s_setprio(0);
    __builtin_amdgcn_s_barrier();
#pragma unroll
    for (int mi = 0; mi < 2; ++mi) {
      af[mi][0] = rdA(cur, 1, mi, 0);
      af[mi][1] = rdA(cur, 1, mi, 1);
    }
    if (t + 2 < NT) {
      stage_half(A,  lda, m0, (t + 2) * 64, AOFF(cur, 0));
      stage_half(Bw, K,   n0, (t + 2) * 64, B2OFF(cur));
    }
    __builtin_amdgcn_s_barrier();
    asm volatile("s_waitcnt lgkmcnt(0)" ::: "memory");
    __builtin_amdgcn_s_setprio(1);
    PH_MFMA(1, b0f);
    __builtin_amdgcn_s_setprio(0);
    if (t < NT - 2) asm volatile("s_waitcnt vmcnt(4)" ::: "memory");
    else            asm volatile("s_waitcnt vmcnt(0)" ::: "memory");
    __builtin_amdgcn_s_barrier();
  }

#pragma unroll
  for (int p = 0; p < 2; ++p)
#pragma unroll
    for (int mi = 0; mi < 2; ++mi)
#pragma unroll
      for (int ni = 0; ni < 4; ++ni)
#pragma unroll
        for (int j = 0; j < 4; ++j) {
          int row_g = m0 + p * 128 + wr * 32 + mi * 16 + lg * 4 + j;
          int col_g = n0 + wc * 64 + ni * 16 + l15;
          float v = acc[p][mi][ni][j];
          size_t o = (size_t)row_g * ldc + col_g;
          float gv = g[row_g];
          dout[o] = gv * v + (1.f - gv) * bf2f(omem[o]);
        }
}

// ---------------- gather-GEMM: k_sh/v_sh for the 8 selected rows per (b,h) ----------------
__global__ __launch_bounds__(256) void gsel_kernel(const unsigned short* __restrict__ mem_bf,
                                                   const unsigned short* __restrict__ wkv,
                                                   const int* __restrict__ idx,
                                                   float* __restrict__ kshp,
                                                   float* __restrict__ vshp) {
  __shared__ __align__(16) unsigned short selA[16][2056];
  __shared__ int selL[8];
  const int tid = threadIdx.x;
  const int h = blockIdx.x, b = blockIdx.y;
  const int kvh = h >> 1;
  if (tid < 8) selL[tid] = idx[(b * H_ + h) * KSEL + tid];
  __syncthreads();
#pragma unroll
  for (int it = 0; it < 8; ++it) {
    int i = it * 256 + tid;
    int r = i >> 8, c8 = i & 255;
    *(s16x8*)&selA[r][c8 * 8] =
        *(const s16x8*)(mem_bf + ((size_t)(b * NMEM + selL[r])) * D_ + c8 * 8);
  }
  {
    s16x8 z = {0, 0, 0, 0, 0, 0, 0, 0};
#pragma unroll
    for (int it = 0; it < 8; ++it) {
      int i = it * 256 + tid;
      int r = 8 + (i >> 8), c8 = i & 255;
      *(s16x8*)&selA[r][c8 * 8] = z;
    }
  }
  __syncthreads();
  const int w = tid >> 6, lane = tid & 63;
  const int l15 = lane & 15, lg = lane >> 4;
  f32x4 acc[4];
#pragma unroll
  for (int ni = 0; ni < 4; ++ni) acc[ni] = fzero4();
  const unsigned short* brow[4];
#pragma unroll
  for (int ni = 0; ni < 4; ++ni) {
    int col = w * 64 + ni * 16 + l15;
    brow[ni] = (col < 128)
        ? (wkv + (size_t)(kvh * DH_ + col) * D_)
        : (wkv + (size_t)(KV_ * DH_ + kvh * DH_ + (col - 128)) * D_);
  }
  for (int kt = 0; kt < D_ / 32; ++kt) {
    s16x8 af = *(const s16x8*)&selA[l15][kt * 32 + lg * 8];
#pragma unroll
    for (int ni = 0; ni < 4; ++ni) {
      s16x8 bf_ = *(const s16x8*)(brow[ni] + kt * 32 + lg * 8);
      acc[ni] = __builtin_amdgcn_mfma_f32_16x16x32_bf16(af, bf_, acc[ni], 0, 0, 0);
    }
  }
#pragma unroll
  for (int ni = 0; ni < 4; ++ni)
#pragma unroll
    for (int j = 0; j < 4; ++j) {
      int row = lg * 4 + j;
      int col = w * 64 + ni * 16 + l15;
      if (row < 8) {
        float* outp = (col < 128 ? kshp : vshp) +
                      ((size_t)(b * H_ + h) * KSEL + row) * DH_ + (col & 127);
        *outp = acc[ni][j];
      }
    }
}

// ---------------- merged in-place pairwise RoPE (q + k sections, one launch) ----------------
__global__ __launch_bounds__(256) void rope_ip2_kernel(unsigned short* __restrict__ qkv,
                                                       const float* __restrict__ cosp,
                                                       const float* __restrict__ sinp) {
  int blk = blockIdx.x, tid = threadIdx.x;
  unsigned short* buf;
  int logp, i;
  if (blk < 2048) { buf = qkv;      logp = 10; i = blk * 256 + tid; }
  else            { buf = qkv + D_; logp = 9;  i = (blk - 2048) * 256 + tid; }
  int pp = i * 8;
  int row = pp >> logp;
  int p0 = pp & ((1 << logp) - 1);
  int blk2 = p0 >> 6, dd0 = p0 & 63;
  int b = row >> 11, t = row & 2047;
  const float* cb = cosp + ((size_t)b * T_ + t) * DH_;
  const float* sb = sinp + ((size_t)b * T_ + t) * DH_;
  unsigned short* p1 = buf + (size_t)row * QKVSTR + blk2 * 128 + dd0;
  s16x8 a = *(s16x8*)p1;
  s16x8 b8 = *(s16x8*)(p1 + 64);
  s16x8 o1, o2;
#pragma unroll
  for (int e = 0; e < 8; ++e) {
    float c1 = cb[dd0 + e], s1 = sb[dd0 + e];
    float c2 = cb[dd0 + 64 + e], s2 = sb[dd0 + 64 + e];
    float x1 = bf2f((unsigned short)a[e]), x2 = bf2f((unsigned short)b8[e]);
    o1[e] = (short)f2bf(x1 * c1 - x2 * s1);
    o2[e] = (short)f2bf(x2 * c2 + x1 * s2);
  }
  *(s16x8*)p1 = o1;
  *(s16x8*)(p1 + 64) = o2;
}

// ---------------- C/S partials (8 t-splits, 32-d tiles) ----------------
__global__ __launch_bounds__(256) void cs_kernel(const float* __restrict__ hs,
                                                 const float* __restrict__ cosp,
                                                 const float* __restrict__ sinp,
                                                 float* __restrict__ Cp, float* __restrict__ Sp) {
  __shared__ __align__(16) float hsL[32][128];
  __shared__ __align__(16) float csL[32][32];
  __shared__ __align__(16) float snL[32][32];
  const int tid = threadIdx.x;
  const int j0 = blockIdx.x * 128, d0 = blockIdx.y * 32;
  const int b = blockIdx.z >> 3, sp = blockIdx.z & 7;
  const int dq = (tid & 7) * 4;
  const int jq = (tid >> 3) * 4;
  float4 aC[4], aS[4];
#pragma unroll
  for (int a = 0; a < 4; ++a) {
    aC[a] = make_float4(0.f, 0.f, 0.f, 0.f);
    aS[a] = make_float4(0.f, 0.f, 0.f, 0.f);
  }
  const int csrow = tid >> 3, csc4 = tid & 7;
  for (int tile = 0; tile < 8; ++tile) {
    int t0 = sp * 256 + tile * 32;
    const float4* hs4 = (const float4*)(hs + ((size_t)b * T_ + t0) * D_ + j0);
#pragma unroll
    for (int r = 0; r < 4; ++r) {
      int i = tid + r * 256;
      int row = i >> 5, c4 = i & 31;
      *(float4*)&hsL[row][c4 * 4] = hs4[(size_t)row * (D_ / 4) + c4];
    }
    const float4* cp4 = (const float4*)(cosp + ((size_t)b * T_ + t0) * DH_ + d0);
    const float4* sp4 = (const float4*)(sinp + ((size_t)b * T_ + t0) * DH_ + d0);
    *(float4*)&csL[csrow][csc4 * 4] = cp4[(size_t)csrow * (DH_ / 4) + csc4];
    *(float4*)&snL[csrow][csc4 * 4] = sp4[(size_t)csrow * (DH_ / 4) + csc4];
    __syncthreads();
#pragma unroll 8
    for (int tt = 0; tt < 32; ++tt) {
      float4 cv = *(const float4*)&csL[tt][dq];
      float4 sv = *(const float4*)&snL[tt][dq];
      float4 hv = *(const float4*)&hsL[tt][jq];
      float ca[4] = {cv.x, cv.y, cv.z, cv.w};
      float sa[4] = {sv.x, sv.y, sv.z, sv.w};
#pragma unroll
      for (int a = 0; a < 4; ++a) {
        aC[a].x += ca[a] * hv.x; aC[a].y += ca[a] * hv.y;
        aC[a].z += ca[a] * hv.z; aC[a].w += ca[a] * hv.w;
        aS[a].x += sa[a] * hv.x; aS[a].y += sa[a] * hv.y;
        aS[a].z += sa[a] * hv.z; aS[a].w += sa[a] * hv.w;
      }
    }
    __syncthreads();
  }
#pragma unroll
  for (int a = 0; a < 4; ++a) {
    size_t o = ((size_t)(sp * B_ + b) * DH_ + d0 + dq + a) * D_ + j0 + jq;
    *(float4*)&Cp[o] = aC[a];
    *(float4*)&Sp[o] = aS[a];
  }
}

// ---------------- reduce 8 partials -> Cr/Sr ----------------
__global__ __launch_bounds__(256) void reduce_cs_kernel(const float4* __restrict__ Cp,
                                                        const float4* __restrict__ Sp,
                                                        float4* __restrict__ Cr,
                                                        float4* __restrict__ Sr) {
  int i = blockIdx.x * 256 + threadIdx.x;
  const int str = (B_ * DH_ * D_) / 4;
  float4 c = Cp[i], s = Sp[i];
#pragma unroll
  for (int p = 1; p < 8; ++p) {
    float4 cp = Cp[i + (size_t)p * str], sq = Sp[i + (size_t)p * str];
    c.x += cp.x; c.y += cp.y; c.z += cp.z; c.w += cp.w;
    s.x += sq.x; s.y += sq.y; s.z += sq.z; s.w += sq.w;
  }
  Cr[i] = c; Sr[i] = s;
}

// ---------------- q_chunk[b,h,d] from reduced C/S (exact fp32) ----------------
__global__ __launch_bounds__(256) void qchunk_kernel(const float* __restrict__ Wq,
                                                     const float* __restrict__ Cr,
                                                     const float* __restrict__ Sr,
                                                     float* __restrict__ qc) {
  int gid = blockIdx.x * 256 + threadIdx.x;
  int wid = gid >> 6, lane = gid & 63;
  int b = wid >> 11, rem = wid & 2047;
  int h = rem >> 7, d = rem & 127;
  const float* w1 = Wq + (size_t)(h * DH_ + d) * D_;
  int dp = (d < 64) ? d + 64 : d - 64;
  float sgn = (d < 64) ? -1.f : 1.f;
  const float* w2 = Wq + (size_t)(h * DH_ + dp) * D_;
  const float* crow = Cr + ((size_t)b * DH_ + d) * D_;
  const float* srow = Sr + ((size_t)b * DH_ + d) * D_;
  float a1 = 0.f, a2 = 0.f;
  for (int j = lane; j < D_; j += 64) { a1 += w1[j] * crow[j]; a2 += w2[j] * srow[j]; }
#pragma unroll
  for (int off = 1; off < 64; off <<= 1) { a1 += __shfl_xor(a1, off); a2 += __shfl_xor(a2, off); }
  if (lane == 0) qc[wid] = (a1 + sgn * a2) * (1.f / (float)T_);
}

// ---------------- z[b,h,j] = sum_d qc[b,h,d] * Wk[kvh*128+d][j] ----------------
__global__ __launch_bounds__(256) void zk_kernel(const float* __restrict__ qc,
                                                 const float* __restrict__ Wk,
                                                 float* __restrict__ z) {
  int j = blockIdx.x * 256 + threadIdx.x;
  int h = blockIdx.y, b = blockIdx.z;
  int kvh = h >> 1;
  const float* qcl = qc + ((size_t)b * H_ + h) * DH_;
  const float* wb = Wk + (size_t)kvh * DH_ * D_ + j;
  float acc = 0.f;
#pragma unroll 8
  for (int d = 0; d < 128; ++d) acc += qcl[d] * wb[(size_t)d * D_];
  z[((size_t)b * H_ + h) * D_ + j] = acc;
}

// ---------------- sim[b,h,n] = kScale * z[b,h,:] . mem[b,n,:] ----------------
__global__ __launch_bounds__(256) void sim_kernel(const float* __restrict__ z,
                                                  const float* __restrict__ mem,
                                                  float* __restrict__ sim) {
  __shared__ float4 mL[16 * 512];
  int tid = threadIdx.x;
  int n0 = blockIdx.x * 16, b = blockIdx.y;
  const float4* mem4 = (const float4*)(mem + (size_t)b * NMEM * D_);
#pragma unroll
  for (int c = 0; c < 32; ++c) {
    int i = tid + c * 256;
    int r = i >> 9, j4 = i & 511;
    mL[r * 512 + (j4 ^ (r & 7))] = mem4[(size_t)(n0 + r) * 512 + j4];
  }
  __syncthreads();
  int h = tid >> 4, n = tid & 15;
  const float4* zr = (const float4*)(z + ((size_t)b * H_ + h) * D_);
  float acc = 0.f;
  for (int j4 = 0; j4 < 512; ++j4) {
    float4 zz = zr[j4];
    float4 mm = mL[n * 512 + (j4 ^ (n & 7))];
    acc += zz.x * mm.x + zz.y * mm.y + zz.z * mm.z + zz.w * mm.w;
  }
  sim[((size_t)b * H_ + h) * NMEM + n0 + n] = acc * kScale;
}

// ---------------- top-8 per (b,h) ----------------
__global__ __launch_bounds__(256) void topk_kernel(const float* __restrict__ sim,
                                                   int* __restrict__ idx) {
  __shared__ float sL[1024];
  __shared__ float rv[256];
  __shared__ int ri[256];
  int tid = threadIdx.x;
  int h = blockIdx.x, b = blockIdx.y;
  const float* sp = sim + ((size_t)b * H_ + h) * NMEM;
#pragma unroll
  for (int r = 0; r < 4; ++r) sL[tid + r * 256] = sp[tid + r * 256];
  __syncthreads();
  for (int kk = 0; kk < 8; ++kk) {
    float bv = -INFINITY; int bi = 0x7fffffff;
#pragma unroll
    for (int r = 0; r < 4; ++r) {
      int i = tid + r * 256;
      float v = sL[i];
      if (v > bv || (v == bv && i < bi)) { bv = v; bi = i; }
    }
    rv[tid] = bv; ri[tid] = bi;
    __syncthreads();
    for (int s = 128; s > 0; s >>= 1) {
      if (tid < s) {
        float v2 = rv[tid + s]; int i2 = ri[tid + s];
        if (v2 > rv[tid] || (v2 == rv[tid] && i2 < ri[tid])) { rv[tid] = v2; ri[tid] = i2; }
      }
      __syncthreads();
    }
    if (tid == 0) { idx[((size_t)b * H_ + h) * KSEL + kk] = ri[0]; sL[ri[0]] = -INFINITY; }
    __syncthreads();
  }
}

// ---------------- memory-branch attention (fp32 ksh/vsh) ----------------
__global__ __launch_bounds__(256) void memattn_kernel(const unsigned short* __restrict__ qbf,
                                                      const float* __restrict__ ksh,
                                                      const float* __restrict__ vsh,
                                                      unsigned short* __restrict__ omem) {
  __shared__ float kl[8][128];
  __shared__ float vl[8][128];
  int tid = threadIdx.x;
  int b = blockIdx.z, h = blockIdx.y, t = blockIdx.x * 256 + tid;
  const float* ks = ksh + ((size_t)b * H_ + h) * KSEL * DH_;
  const float* vs = vsh + ((size_t)b * H_ + h) * KSEL * DH_;
#pragma unroll
  for (int r = 0; r < 4; ++r) {
    int i = tid + r * 256;
    ((float*)kl)[i] = ks[i];
    ((float*)vl)[i] = vs[i];
  }
  __syncthreads();
  float sc[8] = {0.f,0.f,0.f,0.f,0.f,0.f,0.f,0.f};
  const unsigned short* qr = qbf + (size_t)(b * T_ + t) * QKVSTR + h * DH_;
  for (int c = 0; c < 4; ++c) {
    const s16x8* qp = (const s16x8*)(qr + c * 32);
#pragma unroll
    for (int u = 0; u < 4; ++u) {
      s16x8 q8 = qp[u];
#pragma unroll
      for (int e = 0; e < 8; ++e) {
        float qv = bf2f((unsigned short)q8[e]);
        int d = c * 32 + u * 8 + e;
#pragma unroll
        for (int kk = 0; kk < 8; ++kk) sc[kk] += qv * kl[kk][d];
      }
    }
  }
  float sm[8], mx = -INFINITY;
#pragma unroll
  for (int kk = 0; kk < 8; ++kk) { sm[kk] = sc[kk] * kScale; mx = fmaxf(mx, sm[kk]); }
  float sum = 0.f;
#pragma unroll
  for (int kk = 0; kk < 8; ++kk) { sm[kk] = __expf(sm[kk] - mx); sum += sm[kk]; }
  float inv = 1.f / sum;
#pragma unroll
  for (int kk = 0; kk < 8; ++kk) sm[kk] *= inv;
  unsigned short* orow = omem + (size_t)(b * T_ + t) * D_ + h * DH_;
  for (int d = 0; d < 128; d += 4) {
    float o0 = 0.f, o1 = 0.f, o2 = 0.f, o3 = 0.f;
#pragma unroll
    for (int kk = 0; kk < 8; ++kk) {
      float w = sm[kk];
      o0 += w * vl[kk][d + 0];
      o1 += w * vl[kk][d + 1];
      o2 += w * vl[kk][d + 2];
      o3 += w * vl[kk][d + 3];
    }
    uint2 pk;
    pk.x = (unsigned)f2bf(o0) | ((unsigned)f2bf(o1) << 16);
    pk.y = (unsigned)f2bf(o2) | ((unsigned)f2bf(o3) << 16);
    *(uint2*)(orow + d) = pk;
  }
}

// ---------------- gate ----------------
__global__ __launch_bounds__(256) void gate_kernel(const float* __restrict__ hs,
                                                   const float* __restrict__ Wg,
                                                   const float* __restrict__ bg,
                                                   float* __restrict__ g) {
  int gid = blockIdx.x * 256 + threadIdx.x;
  int row = gid >> 6, lane = gid & 63;
  const float4* hr = (const float4*)(hs + (size_t)row * D_);
  const float4* wg4 = (const float4*)Wg;
  float acc = 0.f;
#pragma unroll
  for (int it = 0; it < 8; ++it) {
    float4 hv = hr[lane + it * 64], wv = wg4[lane + it * 64];
    acc += hv.x * wv.x + hv.y * wv.y + hv.z * wv.z + hv.w * wv.w;
  }
#pragma unroll
  for (int off = 1; off < 64; off <<= 1) acc += __shfl_xor(acc, off);
  if (lane == 0) g[row] = 1.f / (1.f + __expf(-(acc + bg[0])));
}

// ---------------- local sliding-window attention (GQA head-pair shared K/V; 8 waves) ----------------
__global__ __launch_bounds__(512) void localattn_kernel(const unsigned short* __restrict__ qbf,
                                                        const unsigned short* __restrict__ kbf,
                                                        const unsigned short* __restrict__ vbf,
                                                        unsigned short* __restrict__ olocal) {
  __shared__ __align__(16) unsigned short kL[2][32][128];
  __shared__ __align__(16) unsigned short vL[2][128][32];
  __shared__ __align__(16) unsigned short pl[8][16][40];
  const int tid = threadIdx.x;
  const int w = tid >> 6, lane = tid & 63;
  const int tb = blockIdx.x * 64;
  const int kvh = blockIdx.y, b = blockIdx.z;
  const int h = kvh * 2 + (w >> 2);          // waves 0-3: head 2kvh, waves 4-7: head 2kvh+1
  const int t0 = tb + (w & 3) * 16;
  const int l15 = lane & 15, lg = lane >> 4;

  s16x8 qf[4];
  {
    const unsigned short* qb = qbf + ((size_t)(b * T_ + t0 + l15) * QKVSTR) + h * DH_ + lg * 8;
#pragma unroll
    for (int kb = 0; kb < 4; ++kb) qf[kb] = *(const s16x8*)(qb + kb * 32);
  }
  f32x4 of[8];
#pragma unroll
  for (int nb = 0; nb < 8; ++nb) of[nb] = fzero4();
  float m_r[4] = {-INFINITY, -INFINITY, -INFINITY, -INFINITY};
  float l_r[4] = {0.f, 0.f, 0.f, 0.f};

  int sstart = tb - (WWIN - 1);
  if (sstart < 0) sstart = 0;
  sstart &= ~31;
  const int slast = tb + 63;
  int wlow = t0 - (WWIN - 1);
  if (wlow < 0) wlow = 0;
  wlow &= ~31;
  const int whigh = t0 + 15;

  const int vk = tid & 15, vcg = (tid >> 4) & 15;
  auto STAGE = [&](int buf, int s0) {
    // K tile: 512 chunks of 16B, one gld_lds per thread
    {
      int s = tid;
      int r = s >> 4, cs = s & 15;
      int cg = cs ^ (r & 7);
      const unsigned short* src = kbf + (size_t)(b * T_ + s0 + r) * QKVSTR + kvh * DH_ + cg * 8;
      __builtin_amdgcn_global_load_lds((const __attribute__((address_space(1))) void*)src,
          (__attribute__((address_space(3))) void*)((char*)&kL[buf][0][0] + w * 1024), 16, 0, 0);
    }
    // V tile: reg-staged transpose by threads 0-255 only (same mapping as before)
    if (tid < 256) {
      int r0 = 2 * vk;
      const unsigned short* vs = vbf + (size_t)(b * T_ + s0 + r0) * QKVSTR + kvh * DH_ + vcg * 8;
      s16x8 va = *(const s16x8*)vs;
      s16x8 vb2 = *(const s16x8*)(vs + QKVSTR);
      int q = vk >> 2;
      int colbase = 2 * (vk & 3);
#pragma unroll
      for (int e = 0; e < 8; ++e) {
        int c = vcg * 8 + e;
        int blk = q ^ ((c >> 2) & 3);
        unsigned int val = (unsigned int)(unsigned short)va[e] |
                           ((unsigned int)(unsigned short)vb2[e] << 16);
        *(unsigned int*)&vL[buf][c][blk * 8 + colbase] = val;
      }
    }
  };

  STAGE(0, sstart);
  int buf = 0;
  const int vp = (l15 >> 2) & 3;
  for (int s0 = sstart; s0 <= slast; s0 += 32, buf ^= 1) {
    __syncthreads();
    if (s0 + 32 <= slast) STAGE(buf ^ 1, s0 + 32);

    if (s0 >= wlow && s0 <= whigh) {
      f32x4 sc[2];
      sc[0] = fzero4(); sc[1] = fzero4();
#pragma unroll
      for (int cb = 0; cb < 2; ++cb) {
#pragma unroll
        for (int kb = 0; kb < 4; ++kb) {
          int r = cb * 16 + l15;
          int c = kb * 4 + lg;
          s16x8 kf = *(const s16x8*)((char*)&kL[buf][0][0] + r * 256 + ((c ^ (r & 7)) * 16));
          sc[cb] = __builtin_amdgcn_mfma_f32_16x16x32_bf16(qf[kb], kf, sc[cb], 0, 0, 0);
        }
      }
      float pv[2][4];
#pragma unroll
      for (int j = 0; j < 4; ++j) {
        int t = t0 + lg * 4 + j;
        int s_a = s0 + l15, s_b = s_a + 16;
        float va = sc[0][j] * kScale;
        float vb = sc[1][j] * kScale;
        va = (s_a <= t && s_a + (WWIN - 1) >= t) ? va : -INFINITY;
        vb = (s_b <= t && s_b + (WWIN - 1) >= t) ? vb : -INFINITY;
        float mx = fmaxf(va, vb);
#pragma unroll
        for (int off = 1; off < 16; off <<= 1) mx = fmaxf(mx, __shfl_xor(mx, off));
        float mn = fmaxf(m_r[j], mx);
        float alpha, pa, pb;
        if (mn == -INFINITY) { alpha = 1.f; pa = 0.f; pb = 0.f; }
        else {
          alpha = __expf(m_r[j] - mn);
          pa = __expf(va - mn);
          pb = __expf(vb - mn);
        }
        m_r[j] = mn;
        float rs = pa + pb;
#pragma unroll
        for (int off = 1; off < 16; off <<= 1) rs += __shfl_xor(rs, off);
        l_r[j] = l_r[j] * alpha + rs;
#pragma unroll
        for (int nb = 0; nb < 8; ++nb) of[nb][j] *= alpha;
        pv[0][j] = pa; pv[1][j] = pb;
      }
#pragma unroll
      for (int cb = 0; cb < 2; ++cb)
#pragma unroll
        for (int j = 0; j < 4; ++j)
          pl[w][lg * 4 + j][cb * 16 + l15] = f2bf(pv[cb][j]);
      asm volatile("s_waitcnt lgkmcnt(0)" ::: "memory");
      __builtin_amdgcn_sched_barrier(0);
      s16x8 pa8 = *(const s16x8*)&pl[w][l15][lg * 8];
#pragma unroll
      for (int nb = 0; nb < 8; ++nb) {
        int c = nb * 16 + l15;
        s16x8 vf = *(const s16x8*)&vL[buf][c][(lg ^ vp) * 8];
        of[nb] = __builtin_amdgcn_mfma_f32_16x16x32_bf16(pa8, vf, of[nb], 0, 0, 0);
      }
    }
  }

  float inv[4];
#pragma unroll
  for (int j = 0; j < 4; ++j) inv[j] = 1.f / l_r[j];
#pragma unroll
  for (int nb = 0; nb < 8; ++nb)
#pragma unroll
    for (int j = 0; j < 4; ++j) {
      int t = t0 + lg * 4 + j;
      olocal[(size_t)(b * T_ + t) * QKVSTR + h * DH_ + nb * 16 + l15] = f2bf(of[nb][j] * inv[j]);
    }
}

// ---------------- host launcher ----------------
extern "C" void kernel_launch(void* const* d_in, const int* in_sizes, int n_in,
                              void* d_out, int out_size, void* d_ws, size_t ws_size,
                              hipStream_t stream) {
  const float* hs   = (const float*)d_in[0];
  const float* cosp = (const float*)d_in[1];
  const float* sinp = (const float*)d_in[2];
  const float* mem  = (const float*)d_in[3];
  const float* Wq   = (const float*)d_in[4];
  const float* Wk   = (const float*)d_in[5];
  const float* Wv   = (const float*)d_in[6];
  const float* Wo   = (const float*)d_in[7];
  const float* Wg   = (const float*)d_in[8];
  const float* bg   = (const float*)d_in[9];
  float* out = (float*)d_out;

  char* p = (char*)d_ws;
  auto alloc = [&](size_t bytes) { char* r = p; p += (bytes + 255) & ~(size_t)255; return r; };
  float* qc     = (float*)alloc((size_t)B_ * H_ * DH_ * 4);
  float* gbuf   = (float*)alloc((size_t)BT * 4);
  float* zbuf   = (float*)alloc((size_t)B_ * H_ * D_ * 4);
  float* simbuf = (float*)alloc((size_t)B_ * H_ * NMEM * 4);
  int*   idxbuf = (int*)alloc((size_t)B_ * H_ * KSEL * 4);
  float* ksh    = (float*)alloc((size_t)B_ * H_ * KSEL * DH_ * 4);
  float* vsh    = (float*)alloc((size_t)B_ * H_ * KSEL * DH_ * 4);
  unsigned short* hs_bf   = (unsigned short*)alloc((size_t)BT * D_ * 2);       // -> o_mem bf16 later
  unsigned short* qkv_raw = (unsigned short*)alloc((size_t)BT * QKVSTR * 2);   // q|k|v merged; q -> o_local in place
  unsigned short* wbig    = (unsigned short*)alloc((size_t)2 * D_ * D_ * 2);   // Wq|Wk|Wv stack
  unsigned short* mem_bf  = (unsigned short*)alloc((size_t)B_ * NMEM * D_ * 2);
  float* crsr             = (float*)alloc((size_t)2 * B_ * DH_ * D_ * 4);      // Cr|Sr

  // C/S partials live in d_out (33.5 MB; fully rewritten by final GEMM)
  float* Cp = (float*)d_out;
  float* Sp = Cp + (size_t)8 * B_ * DH_ * D_;
  float* Cr = crsr;
  float* Sr = Cr + (size_t)B_ * DH_ * D_;
  unsigned short* omem_bf = hs_bf;

  // 1) conversions + merged QKV projection (256^2 8-phase)
  conv_kernel<<<(BT * D_ / 4 + 255) / 256, 256, 0, stream>>>(hs, hs_bf, BT * D_);
  conv_kernel<<<(D_ * D_ / 4 + 255) / 256, 256, 0, stream>>>(Wq, wbig, D_ * D_);
  conv_kernel<<<(KV_ * DH_ * D_ / 4 + 255) / 256, 256, 0, stream>>>(Wk, wbig + (size_t)D_ * D_, KV_ * DH_ * D_);
  conv_kernel<<<(KV_ * DH_ * D_ / 4 + 255) / 256, 256, 0, stream>>>(Wv, wbig + (size_t)D_ * D_ + (size_t)KV_ * DH_ * D_, KV_ * DH_ * D_);
  gemm256<0><<<dim3(QKVSTR / 256, BT / 256), 512, 0, stream>>>(hs_bf, wbig, QKVSTR, D_, D_, QKVSTR, qkv_raw, nullptr, nullptr, nullptr);
  conv_kernel<<<(B_ * NMEM * D_ / 4 + 255) / 256, 256, 0, stream>>>(mem, mem_bf, B_ * NMEM * D_);

  // 2) merged in-place RoPE (q + k sections, one launch)
  rope_ip2_kernel<<<3072, 256, 0, stream>>>(qkv_raw, cosp, sinp);

  // 3) exact-fp32 selection path
  cs_kernel<<<dim3(D_ / 128, DH_ / 32, B_ * 8), 256, 0, stream>>>(hs, cosp, sinp, Cp, Sp);
  reduce_cs_kernel<<<(B_ * DH_ * D_ / 4) / 256, 256, 0, stream>>>((const float4*)Cp, (const float4*)Sp, (float4*)Cr, (float4*)Sr);
  qchunk_kernel<<<(B_ * H_ * DH_) / 4, 256, 0, stream>>>(Wq, Cr, Sr, qc);
  zk_kernel<<<dim3(D_ / 256, H_, B_), 256, 0, stream>>>(qc, Wk, zbuf);
  sim_kernel<<<dim3(NMEM / 16, B_), 256, 0, stream>>>(zbuf, mem, simbuf);
  topk_kernel<<<dim3(H_, B_), 256, 0, stream>>>(simbuf, idxbuf);

  // 4) gather-GEMM for selected K/V rows, then memory-branch attention -> o_mem bf16
  gsel_kernel<<<dim3(H_, B_), 256, 0, stream>>>(mem_bf, wbig + (size_t)D_ * D_, idxbuf, ksh, vsh);
  memattn_kernel<<<dim3(T_ / 256, H_, B_), 256, 0, stream>>>(qkv_raw, ksh, vsh, omem_bf);

  // 5) gate
  gate_kernel<<<BT / 4, 256, 0, stream>>>(hs, Wg, bg, gbuf);

  // 6) local sliding-window attention (GQA pair-shared K/V; writes o_local in place)
  localattn_kernel<<<dim3(T_ / 64, KV_, B_), 512, 0, stream>>>(qkv_raw, qkv_raw + D_, qkv_raw + D_ + KV_ * DH_, qkv_raw);

  // 7) Wo projection + final combine (256x128 tile -> 256 blocks, full machine)
  conv_kernel<<<(D_ * D_ / 4 + 255) / 256, 256, 0, stream>>>(Wo, wbig, D_ * D_);
  gemm256n<<<dim3(D_ / 128, BT / 256), 512, 0, stream>>>(qkv_raw, wbig, D_, D_, QKVSTR, D_, gbuf, omem_bf, out);
}

// Round 21
// 380.392 us; speedup vs baseline: 1.1061x; 1.0164x over previous
//
#include <hip/hip_runtime.h>
#include <stdint.h>

#define B_   2
#define T_   2048
#define D_   2048
#define H_   16
#define KV_  8
#define DH_  128
#define NMEM 1024
#define WWIN 256
#define KSEL 8
#define BT   (B_*T_)
#define QKVSTR 4096   // merged qkv row stride (elements)

__constant__ const float kScale = 0.08838834764831845f; // DH^-0.5

typedef __attribute__((ext_vector_type(8))) short s16x8;
typedef __attribute__((ext_vector_type(4))) float f32x4;

__device__ inline unsigned short f2bf(float f) {
  union { float f; unsigned int u; } c; c.f = f;
  unsigned int u = c.u;
  unsigned int r = u + 0x7fffu + ((u >> 16) & 1u);
  return (unsigned short)(r >> 16);
}
__device__ inline float bf2f(unsigned short v) {
  union { unsigned int u; float f; } c; c.u = ((unsigned int)v) << 16;
  return c.f;
}
__device__ inline f32x4 fzero4() { f32x4 v; v[0]=0.f; v[1]=0.f; v[2]=0.f; v[3]=0.f; return v; }

__device__ inline void conv_one(const float* __restrict__ src, unsigned short* __restrict__ dst,
                                size_t idx) {
  float4 v = ((const float4*)src)[idx];
  uint2 o;
  o.x = (unsigned)f2bf(v.x) | ((unsigned)f2bf(v.y) << 16);
  o.y = (unsigned)f2bf(v.z) | ((unsigned)f2bf(v.w) << 16);
  ((uint2*)dst)[idx] = o;
}

// ---------------- merged conversions: hs + mem (12288 blocks) ----------------
__global__ __launch_bounds__(256) void conv_hm_kernel(const float* __restrict__ hs,
                                                      const float* __restrict__ mem,
                                                      unsigned short* __restrict__ hs_bf,
                                                      unsigned short* __restrict__ mem_bf) {
  int blk = blockIdx.x, tid = threadIdx.x;
  if (blk < 8192) conv_one(hs,  hs_bf,  (size_t)blk * 256 + tid);
  else            conv_one(mem, mem_bf, (size_t)(blk - 8192) * 256 + tid);
}

// ---------------- merged conversions: Wq|Wk|Wv -> wbig, Wo -> wo_bf (12288 blocks) ----------------
__global__ __launch_bounds__(256) void conv_w4_kernel(const float* __restrict__ Wq,
                                                      const float* __restrict__ Wk,
                                                      const float* __restrict__ Wv,
                                                      const float* __restrict__ Wo,
                                                      unsigned short* __restrict__ wbig,
                                                      unsigned short* __restrict__ wo_bf) {
  int blk = blockIdx.x, tid = threadIdx.x;
  if (blk < 4096)       conv_one(Wq, wbig, (size_t)blk * 256 + tid);
  else if (blk < 6144)  conv_one(Wk, wbig + (size_t)D_ * D_, (size_t)(blk - 4096) * 256 + tid);
  else if (blk < 8192)  conv_one(Wv, wbig + (size_t)D_ * D_ + (size_t)KV_ * DH_ * D_, (size_t)(blk - 6144) * 256 + tid);
  else                  conv_one(Wo, wo_bf, (size_t)(blk - 8192) * 256 + tid);
}

// ================= 256x256 8-phase GEMM (T2+T3+T4+T5) =================
#define AOFF(buf, half) ((buf)*32768 + (half)*16384)
#define BOFF(buf, half) (65536 + (buf)*32768 + (half)*16384)

#define PH_MFMA(P, BF) \
  { \
    _Pragma("unroll") \
    for (int mi = 0; mi < 2; ++mi) { \
      _Pragma("unroll") \
      for (int ni = 0; ni < 4; ++ni) { \
        acc[P][mi][ni] = __builtin_amdgcn_mfma_f32_16x16x32_bf16(af[mi][0], BF[ni][0], acc[P][mi][ni], 0, 0, 0); \
        acc[P][mi][ni] = __builtin_amdgcn_mfma_f32_16x16x32_bf16(af[mi][1], BF[ni][1], acc[P][mi][ni], 0, 0, 0); \
      } \
    } \
  }

template<int MODE>
__global__ __launch_bounds__(512, 2) void gemm256(const unsigned short* __restrict__ A,
                                                  const unsigned short* __restrict__ Bw,
                                                  int N, int K, int lda, int ldc,
                                                  unsigned short* __restrict__ Cb,
                                                  const float* __restrict__ g,
                                                  const unsigned short* __restrict__ omem,
                                                  float* __restrict__ dout) {
  __shared__ __align__(16) char lds[131072];
  const int tid = threadIdx.x;
  const int wv = tid >> 6, lane = tid & 63;
  const int l15 = lane & 15, lg = lane >> 4;
  const int wr = wv >> 1, wc = wv & 1;
  const int gx = gridDim.x;
  const int nwg = gx * gridDim.y;
  const int flat = blockIdx.y * gx + blockIdx.x;
  const int chunk = nwg >> 3;
  const int wg = (flat & 7) * chunk + (flat >> 3);
  const int bx = wg % gx, by = wg / gx;
  const int m0 = by * 256, n0 = bx * 256;
  const int NT = K >> 6;

  auto stage_half = [&](const unsigned short* base, int stride, int row0, int koff, int ldsoff) {
#pragma unroll
    for (int ld = 0; ld < 2; ++ld) {
      int s = ld * 512 + tid;
      int row = s >> 3, cs = s & 7;
      int cg = cs ^ (row & 7);
      const unsigned short* src = base + (size_t)(row0 + row) * stride + koff + cg * 8;
      __builtin_amdgcn_global_load_lds((const __attribute__((address_space(1))) void*)src,
          (__attribute__((address_space(3))) void*)(lds + ldsoff + ld * 8192 + wv * 1024), 16, 0, 0);
    }
  };
  auto rdA = [&](int buf, int half, int mi, int kk) -> s16x8 {
    int r = wr * 32 + mi * 16 + l15;
    int slot = (kk * 4 + lg) ^ (r & 7);
    return *(const s16x8*)(lds + AOFF(buf, half) + r * 128 + slot * 16);
  };
  auto rdB = [&](int buf, int half, int ni, int kk) -> s16x8 {
    int r = wc * 64 + ni * 16 + l15;
    int slot = (kk * 4 + lg) ^ (r & 7);
    return *(const s16x8*)(lds + BOFF(buf, half) + r * 128 + slot * 16);
  };

  f32x4 acc[4][2][4];
#pragma unroll
  for (int p = 0; p < 4; ++p)
#pragma unroll
    for (int mi = 0; mi < 2; ++mi)
#pragma unroll
      for (int ni = 0; ni < 4; ++ni) acc[p][mi][ni] = fzero4();

  stage_half(A,  lda, m0,       0,  AOFF(0, 0));
  stage_half(Bw, K,   n0,       0,  BOFF(0, 0));
  stage_half(A,  lda, m0 + 128, 0,  AOFF(0, 1));
  stage_half(Bw, K,   n0 + 128, 0,  BOFF(0, 1));
  stage_half(A,  lda, m0,       64, AOFF(1, 0));
  stage_half(Bw, K,   n0,       64, BOFF(1, 0));
  stage_half(A,  lda, m0 + 128, 64, AOFF(1, 1));
  asm volatile("s_waitcnt vmcnt(6)" ::: "memory");
  __builtin_amdgcn_s_barrier();

  int cur = 0;
  for (int t = 0; t < NT; ++t, cur ^= 1) {
    const int nxt = cur ^ 1;
    s16x8 af[2][2], b0f[4][2], b1f[4][2];
#pragma unroll
    for (int mi = 0; mi < 2; ++mi) {
      af[mi][0] = rdA(cur, 0, mi, 0);
      af[mi][1] = rdA(cur, 0, mi, 1);
    }
#pragma unroll
    for (int ni = 0; ni < 4; ++ni) {
      b0f[ni][0] = rdB(cur, 0, ni, 0);
      b0f[ni][1] = rdB(cur, 0, ni, 1);
    }
    if (t + 1 < NT) stage_half(Bw, K, n0 + 128, (t + 1) * 64, BOFF(nxt, 1));
    __builtin_amdgcn_s_barrier();
    asm volatile("s_waitcnt lgkmcnt(0)" ::: "memory");
    __builtin_amdgcn_s_setprio(1);
    PH_MFMA(0, b0f);
    __builtin_amdgcn_s_setprio(0);
    __builtin_amdgcn_s_barrier();
#pragma unroll
    for (int ni = 0; ni < 4; ++ni) {
      b1f[ni][0] = rdB(cur, 1, ni, 0);
      b1f[ni][1] = rdB(cur, 1, ni, 1);
    }
    if (t + 2 < NT) stage_half(A, lda, m0, (t + 2) * 64, AOFF(cur, 0));
    __builtin_amdgcn_s_barrier();
    asm volatile("s_waitcnt lgkmcnt(0)" ::: "memory");
    __builtin_amdgcn_s_setprio(1);
    PH_MFMA(1, b1f);
    __builtin_amdgcn_s_setprio(0);
    __builtin_amdgcn_s_barrier();
#pragma unroll
    for (int mi = 0; mi < 2; ++mi) {
      af[mi][0] = rdA(cur, 1, mi, 0);
      af[mi][1] = rdA(cur, 1, mi, 1);
    }
    if (t + 2 < NT) stage_half(Bw, K, n0, (t + 2) * 64, BOFF(cur, 0));
    __builtin_amdgcn_s_barrier();
    asm volatile("s_waitcnt lgkmcnt(0)" ::: "memory");
    __builtin_amdgcn_s_setprio(1);
    PH_MFMA(2, b0f);
    __builtin_amdgcn_s_setprio(0);
    __builtin_amdgcn_s_barrier();
    if (t + 2 < NT) stage_half(A, lda, m0 + 128, (t + 2) * 64, AOFF(cur, 1));
    __builtin_amdgcn_s_barrier();
    asm volatile("s_waitcnt lgkmcnt(0)" ::: "memory");
    __builtin_amdgcn_s_setprio(1);
    PH_MFMA(3, b1f);
    __builtin_amdgcn_s_setprio(0);
    if (t < NT - 2) asm volatile("s_waitcnt vmcnt(6)" ::: "memory");
    else            asm volatile("s_waitcnt vmcnt(0)" ::: "memory");
    __builtin_amdgcn_s_barrier();
  }

#pragma unroll
  for (int p = 0; p < 4; ++p)
#pragma unroll
    for (int mi = 0; mi < 2; ++mi)
#pragma unroll
      for (int ni = 0; ni < 4; ++ni)
#pragma unroll
        for (int j = 0; j < 4; ++j) {
          int row_g = m0 + (p >> 1) * 128 + wr * 32 + mi * 16 + lg * 4 + j;
          int col_g = n0 + (p & 1) * 128 + wc * 64 + ni * 16 + l15;
          float v = acc[p][mi][ni][j];
          size_t o = (size_t)row_g * ldc + col_g;
          if constexpr (MODE == 0) {
            Cb[o] = f2bf(v);
          } else {
            float gv = g[row_g];
            dout[o] = gv * v + (1.f - gv) * bf2f(omem[o]);
          }
        }
}

// ================= 256x128 2-phase GEMM (full-machine grid for N=2048) =================
#define B2OFF(buf) (65536 + (buf)*16384)

__global__ __launch_bounds__(512, 2) void gemm256n(const unsigned short* __restrict__ A,
                                                   const unsigned short* __restrict__ Bw,
                                                   int N, int K, int lda, int ldc,
                                                   const float* __restrict__ g,
                                                   const unsigned short* __restrict__ omem,
                                                   float* __restrict__ dout) {
  __shared__ __align__(16) char lds[98304];
  const int tid = threadIdx.x;
  const int wv = tid >> 6, lane = tid & 63;
  const int l15 = lane & 15, lg = lane >> 4;
  const int wr = wv >> 1, wc = wv & 1;
  const int gx = gridDim.x;
  const int nwg = gx * gridDim.y;
  const int flat = blockIdx.y * gx + blockIdx.x;
  const int chunk = nwg >> 3;
  const int wg = (flat & 7) * chunk + (flat >> 3);
  const int bx = wg % gx, by = wg / gx;
  const int m0 = by * 256, n0 = bx * 128;
  const int NT = K >> 6;

  auto stage_half = [&](const unsigned short* base, int stride, int row0, int koff, int ldsoff) {
#pragma unroll
    for (int ld = 0; ld < 2; ++ld) {
      int s = ld * 512 + tid;
      int row = s >> 3, cs = s & 7;
      int cg = cs ^ (row & 7);
      const unsigned short* src = base + (size_t)(row0 + row) * stride + koff + cg * 8;
      __builtin_amdgcn_global_load_lds((const __attribute__((address_space(1))) void*)src,
          (__attribute__((address_space(3))) void*)(lds + ldsoff + ld * 8192 + wv * 1024), 16, 0, 0);
    }
  };
  auto rdA = [&](int buf, int half, int mi, int kk) -> s16x8 {
    int r = wr * 32 + mi * 16 + l15;
    int slot = (kk * 4 + lg) ^ (r & 7);
    return *(const s16x8*)(lds + AOFF(buf, half) + r * 128 + slot * 16);
  };
  auto rdB = [&](int buf, int ni, int kk) -> s16x8 {
    int r = wc * 64 + ni * 16 + l15;
    int slot = (kk * 4 + lg) ^ (r & 7);
    return *(const s16x8*)(lds + B2OFF(buf) + r * 128 + slot * 16);
  };

  f32x4 acc[2][2][4];
#pragma unroll
  for (int p = 0; p < 2; ++p)
#pragma unroll
    for (int mi = 0; mi < 2; ++mi)
#pragma unroll
      for (int ni = 0; ni < 4; ++ni) acc[p][mi][ni] = fzero4();

  stage_half(A,  lda, m0,       0,  AOFF(0, 0));
  stage_half(Bw, K,   n0,       0,  B2OFF(0));
  stage_half(A,  lda, m0 + 128, 0,  AOFF(0, 1));
  stage_half(A,  lda, m0,       64, AOFF(1, 0));
  stage_half(Bw, K,   n0,       64, B2OFF(1));
  asm volatile("s_waitcnt vmcnt(4)" ::: "memory");
  __builtin_amdgcn_s_barrier();

  int cur = 0;
  for (int t = 0; t < NT; ++t, cur ^= 1) {
    const int nxt = cur ^ 1;
    s16x8 af[2][2], b0f[4][2];
#pragma unroll
    for (int mi = 0; mi < 2; ++mi) {
      af[mi][0] = rdA(cur, 0, mi, 0);
      af[mi][1] = rdA(cur, 0, mi, 1);
    }
#pragma unroll
    for (int ni = 0; ni < 4; ++ni) {
      b0f[ni][0] = rdB(cur, ni, 0);
      b0f[ni][1] = rdB(cur, ni, 1);
    }
    if (t + 1 < NT) stage_half(A, lda, m0 + 128, (t + 1) * 64, AOFF(nxt, 1));
    __builtin_amdgcn_s_barrier();
    asm volatile("s_waitcnt lgkmcnt(0)" ::: "memory");
    __builtin_amdgcn_s_setprio(1);
    PH_MFMA(0, b0f);
    __builtin_amdgcn_s_setprio(0);
    __builtin_amdgcn_s_barrier();
#pragma unroll
    for (int mi = 0; mi < 2; ++mi) {
      af[mi][0] = rdA(cur, 1, mi, 0);
      af[mi][1] = rdA(cur, 1, mi, 1);
    }
    if (t + 2 < NT) {
      stage_half(A,  lda, m0, (t + 2) * 64, AOFF(cur, 0));
      stage_half(Bw, K,   n0, (t + 2) * 64, B2OFF(cur));
    }
    __builtin_amdgcn_s_barrier();
    asm volatile("s_waitcnt lgkmcnt(0)" ::: "memory");
    __builtin_amdgcn_s_setprio(1);
    PH_MFMA(1, b0f);
    __builtin_amdgcn_s_setprio(0);
    if (t < NT - 2) asm volatile("s_waitcnt vmcnt(4)" ::: "memory");
    else            asm volatile("s_waitcnt vmcnt(0)" ::: "memory");
    __builtin_amdgcn_s_barrier();
  }

#pragma unroll
  for (int p = 0; p < 2; ++p)
#pragma unroll
    for (int mi = 0; mi < 2; ++mi)
#pragma unroll
      for (int ni = 0; ni < 4; ++ni)
#pragma unroll
        for (int j = 0; j < 4; ++j) {
          int row_g = m0 + p * 128 + wr * 32 + mi * 16 + lg * 4 + j;
          int col_g = n0 + wc * 64 + ni * 16 + l15;
          float v = acc[p][mi][ni][j];
          size_t o = (size_t)row_g * ldc + col_g;
          float gv = g[row_g];
          dout[o] = gv * v + (1.f - gv) * bf2f(omem[o]);
        }
}

// ---------------- gather-GEMM: k_sh/v_sh for the 8 selected rows per (b,h) ----------------
__global__ __launch_bounds__(256) void gsel_kernel(const unsigned short* __restrict__ mem_bf,
                                                   const unsigned short* __restrict__ wkv,
                                                   const int* __restrict__ idx,
                                                   float* __restrict__ kshp,
                                                   float* __restrict__ vshp) {
  __shared__ __align__(16) unsigned short selA[16][2056];
  __shared__ int selL[8];
  const int tid = threadIdx.x;
  const int h = blockIdx.x, b = blockIdx.y;
  const int kvh = h >> 1;
  if (tid < 8) selL[tid] = idx[(b * H_ + h) * KSEL + tid];
  __syncthreads();
#pragma unroll
  for (int it = 0; it < 8; ++it) {
    int i = it * 256 + tid;
    int r = i >> 8, c8 = i & 255;
    *(s16x8*)&selA[r][c8 * 8] =
        *(const s16x8*)(mem_bf + ((size_t)(b * NMEM + selL[r])) * D_ + c8 * 8);
  }
  {
    s16x8 z = {0, 0, 0, 0, 0, 0, 0, 0};
#pragma unroll
    for (int it = 0; it < 8; ++it) {
      int i = it * 256 + tid;
      int r = 8 + (i >> 8), c8 = i & 255;
      *(s16x8*)&selA[r][c8 * 8] = z;
    }
  }
  __syncthreads();
  const int w = tid >> 6, lane = tid & 63;
  const int l15 = lane & 15, lg = lane >> 4;
  f32x4 acc[4];
#pragma unroll
  for (int ni = 0; ni < 4; ++ni) acc[ni] = fzero4();
  const unsigned short* brow[4];
#pragma unroll
  for (int ni = 0; ni < 4; ++ni) {
    int col = w * 64 + ni * 16 + l15;
    brow[ni] = (col < 128)
        ? (wkv + (size_t)(kvh * DH_ + col) * D_)
        : (wkv + (size_t)(KV_ * DH_ + kvh * DH_ + (col - 128)) * D_);
  }
  for (int kt = 0; kt < D_ / 32; ++kt) {
    s16x8 af = *(const s16x8*)&selA[l15][kt * 32 + lg * 8];
#pragma unroll
    for (int ni = 0; ni < 4; ++ni) {
      s16x8 bf_ = *(const s16x8*)(brow[ni] + kt * 32 + lg * 8);
      acc[ni] = __builtin_amdgcn_mfma_f32_16x16x32_bf16(af, bf_, acc[ni], 0, 0, 0);
    }
  }
#pragma unroll
  for (int ni = 0; ni < 4; ++ni)
#pragma unroll
    for (int j = 0; j < 4; ++j) {
      int row = lg * 4 + j;
      int col = w * 64 + ni * 16 + l15;
      if (row < 8) {
        float* outp = (col < 128 ? kshp : vshp) +
                      ((size_t)(b * H_ + h) * KSEL + row) * DH_ + (col & 127);
        *outp = acc[ni][j];
      }
    }
}

// ---------------- merged in-place pairwise RoPE (q + k sections, one launch) ----------------
__global__ __launch_bounds__(256) void rope_ip2_kernel(unsigned short* __restrict__ qkv,
                                                       const float* __restrict__ cosp,
                                                       const float* __restrict__ sinp) {
  int blk = blockIdx.x, tid = threadIdx.x;
  unsigned short* buf;
  int logp, i;
  if (blk < 2048) { buf = qkv;      logp = 10; i = blk * 256 + tid; }
  else            { buf = qkv + D_; logp = 9;  i = (blk - 2048) * 256 + tid; }
  int pp = i * 8;
  int row = pp >> logp;
  int p0 = pp & ((1 << logp) - 1);
  int blk2 = p0 >> 6, dd0 = p0 & 63;
  int b = row >> 11, t = row & 2047;
  const float* cb = cosp + ((size_t)b * T_ + t) * DH_;
  const float* sb = sinp + ((size_t)b * T_ + t) * DH_;
  unsigned short* p1 = buf + (size_t)row * QKVSTR + blk2 * 128 + dd0;
  s16x8 a = *(s16x8*)p1;
  s16x8 b8 = *(s16x8*)(p1 + 64);
  s16x8 o1, o2;
#pragma unroll
  for (int e = 0; e < 8; ++e) {
    float c1 = cb[dd0 + e], s1 = sb[dd0 + e];
    float c2 = cb[dd0 + 64 + e], s2 = sb[dd0 + 64 + e];
    float x1 = bf2f((unsigned short)a[e]), x2 = bf2f((unsigned short)b8[e]);
    o1[e] = (short)f2bf(x1 * c1 - x2 * s1);
    o2[e] = (short)f2bf(x2 * c2 + x1 * s2);
  }
  *(s16x8*)p1 = o1;
  *(s16x8*)(p1 + 64) = o2;
}

// ---------------- C/S partials (8 t-splits, 32-d tiles) ----------------
__global__ __launch_bounds__(256) void cs_kernel(const float* __restrict__ hs,
                                                 const float* __restrict__ cosp,
                                                 const float* __restrict__ sinp,
                                                 float* __restrict__ Cp, float* __restrict__ Sp) {
  __shared__ __align__(16) float hsL[32][128];
  __shared__ __align__(16) float csL[32][32];
  __shared__ __align__(16) float snL[32][32];
  const int tid = threadIdx.x;
  const int j0 = blockIdx.x * 128, d0 = blockIdx.y * 32;
  const int b = blockIdx.z >> 3, sp = blockIdx.z & 7;
  const int dq = (tid & 7) * 4;
  const int jq = (tid >> 3) * 4;
  float4 aC[4], aS[4];
#pragma unroll
  for (int a = 0; a < 4; ++a) {
    aC[a] = make_float4(0.f, 0.f, 0.f, 0.f);
    aS[a] = make_float4(0.f, 0.f, 0.f, 0.f);
  }
  const int csrow = tid >> 3, csc4 = tid & 7;
  for (int tile = 0; tile < 8; ++tile) {
    int t0 = sp * 256 + tile * 32;
    const float4* hs4 = (const float4*)(hs + ((size_t)b * T_ + t0) * D_ + j0);
#pragma unroll
    for (int r = 0; r < 4; ++r) {
      int i = tid + r * 256;
      int row = i >> 5, c4 = i & 31;
      *(float4*)&hsL[row][c4 * 4] = hs4[(size_t)row * (D_ / 4) + c4];
    }
    const float4* cp4 = (const float4*)(cosp + ((size_t)b * T_ + t0) * DH_ + d0);
    const float4* sp4 = (const float4*)(sinp + ((size_t)b * T_ + t0) * DH_ + d0);
    *(float4*)&csL[csrow][csc4 * 4] = cp4[(size_t)csrow * (DH_ / 4) + csc4];
    *(float4*)&snL[csrow][csc4 * 4] = sp4[(size_t)csrow * (DH_ / 4) + csc4];
    __syncthreads();
#pragma unroll 8
    for (int tt = 0; tt < 32; ++tt) {
      float4 cv = *(const float4*)&csL[tt][dq];
      float4 sv = *(const float4*)&snL[tt][dq];
      float4 hv = *(const float4*)&hsL[tt][jq];
      float ca[4] = {cv.x, cv.y, cv.z, cv.w};
      float sa[4] = {sv.x, sv.y, sv.z, sv.w};
#pragma unroll
      for (int a = 0; a < 4; ++a) {
        aC[a].x += ca[a] * hv.x; aC[a].y += ca[a] * hv.y;
        aC[a].z += ca[a] * hv.z; aC[a].w += ca[a] * hv.w;
        aS[a].x += sa[a] * hv.x; aS[a].y += sa[a] * hv.y;
        aS[a].z += sa[a] * hv.z; aS[a].w += sa[a] * hv.w;
      }
    }
    __syncthreads();
  }
#pragma unroll
  for (int a = 0; a < 4; ++a) {
    size_t o = ((size_t)(sp * B_ + b) * DH_ + d0 + dq + a) * D_ + j0 + jq;
    *(float4*)&Cp[o] = aC[a];
    *(float4*)&Sp[o] = aS[a];
  }
}

// ---------------- reduce 8 partials -> Cr/Sr ----------------
__global__ __launch_bounds__(256) void reduce_cs_kernel(const float4* __restrict__ Cp,
                                                        const float4* __restrict__ Sp,
                                                        float4* __restrict__ Cr,
                                                        float4* __restrict__ Sr) {
  int i = blockIdx.x * 256 + threadIdx.x;
  const int str = (B_ * DH_ * D_) / 4;
  float4 c = Cp[i], s = Sp[i];
#pragma unroll
  for (int p = 1; p < 8; ++p) {
    float4 cp = Cp[i + (size_t)p * str], sq = Sp[i + (size_t)p * str];
    c.x += cp.x; c.y += cp.y; c.z += cp.z; c.w += cp.w;
    s.x += sq.x; s.y += sq.y; s.z += sq.z; s.w += sq.w;
  }
  Cr[i] = c; Sr[i] = s;
}

// ---------------- q_chunk[b,h,d] from reduced C/S (exact fp32) ----------------
__global__ __launch_bounds__(256) void qchunk_kernel(const float* __restrict__ Wq,
                                                     const float* __restrict__ Cr,
                                                     const float* __restrict__ Sr,
                                                     float* __restrict__ qc) {
  int gid = blockIdx.x * 256 + threadIdx.x;
  int wid = gid >> 6, lane = gid & 63;
  int b = wid >> 11, rem = wid & 2047;
  int h = rem >> 7, d = rem & 127;
  const float* w1 = Wq + (size_t)(h * DH_ + d) * D_;
  int dp = (d < 64) ? d + 64 : d - 64;
  float sgn = (d < 64) ? -1.f : 1.f;
  const float* w2 = Wq + (size_t)(h * DH_ + dp) * D_;
  const float* crow = Cr + ((size_t)b * DH_ + d) * D_;
  const float* srow = Sr + ((size_t)b * DH_ + d) * D_;
  float a1 = 0.f, a2 = 0.f;
  for (int j = lane; j < D_; j += 64) { a1 += w1[j] * crow[j]; a2 += w2[j] * srow[j]; }
#pragma unroll
  for (int off = 1; off < 64; off <<= 1) { a1 += __shfl_xor(a1, off); a2 += __shfl_xor(a2, off); }
  if (lane == 0) qc[wid] = (a1 + sgn * a2) * (1.f / (float)T_);
}

// ---------------- z[b,h,j] = sum_d qc[b,h,d] * Wk[kvh*128+d][j] ----------------
__global__ __launch_bounds__(256) void zk_kernel(const float* __restrict__ qc,
                                                 const float* __restrict__ Wk,
                                                 float* __restrict__ z) {
  int j = blockIdx.x * 256 + threadIdx.x;
  int h = blockIdx.y, b = blockIdx.z;
  int kvh = h >> 1;
  const float* qcl = qc + ((size_t)b * H_ + h) * DH_;
  const float* wb = Wk + (size_t)kvh * DH_ * D_ + j;
  float acc = 0.f;
#pragma unroll 8
  for (int d = 0; d < 128; ++d) acc += qcl[d] * wb[(size_t)d * D_];
  z[((size_t)b * H_ + h) * D_ + j] = acc;
}

// ---------------- sim[b,h,n] = kScale * z[b,h,:] . mem[b,n,:] ----------------
__global__ __launch_bounds__(256) void sim_kernel(const float* __restrict__ z,
                                                  const float* __restrict__ mem,
                                                  float* __restrict__ sim) {
  __shared__ float4 mL[16 * 512];
  int tid = threadIdx.x;
  int n0 = blockIdx.x * 16, b = blockIdx.y;
  const float4* mem4 = (const float4*)(mem + (size_t)b * NMEM * D_);
#pragma unroll
  for (int c = 0; c < 32; ++c) {
    int i = tid + c * 256;
    int r = i >> 9, j4 = i & 511;
    mL[r * 512 + (j4 ^ (r & 7))] = mem4[(size_t)(n0 + r) * 512 + j4];
  }
  __syncthreads();
  int h = tid >> 4, n = tid & 15;
  const float4* zr = (const float4*)(z + ((size_t)b * H_ + h) * D_);
  float acc = 0.f;
  for (int j4 = 0; j4 < 512; ++j4) {
    float4 zz = zr[j4];
    float4 mm = mL[n * 512 + (j4 ^ (n & 7))];
    acc += zz.x * mm.x + zz.y * mm.y + zz.z * mm.z + zz.w * mm.w;
  }
  sim[((size_t)b * H_ + h) * NMEM + n0 + n] = acc * kScale;
}

// ---------------- top-8 per (b,h) ----------------
__global__ __launch_bounds__(256) void topk_kernel(const float* __restrict__ sim,
                                                   int* __restrict__ idx) {
  __shared__ float sL[1024];
  __shared__ float rv[256];
  __shared__ int ri[256];
  int tid = threadIdx.x;
  int h = blockIdx.x, b = blockIdx.y;
  const float* sp = sim + ((size_t)b * H_ + h) * NMEM;
#pragma unroll
  for (int r = 0; r < 4; ++r) sL[tid + r * 256] = sp[tid + r * 256];
  __syncthreads();
  for (int kk = 0; kk < 8; ++kk) {
    float bv = -INFINITY; int bi = 0x7fffffff;
#pragma unroll
    for (int r = 0; r < 4; ++r) {
      int i = tid + r * 256;
      float v = sL[i];
      if (v > bv || (v == bv && i < bi)) { bv = v; bi = i; }
    }
    rv[tid] = bv; ri[tid] = bi;
    __syncthreads();
    for (int s = 128; s > 0; s >>= 1) {
      if (tid < s) {
        float v2 = rv[tid + s]; int i2 = ri[tid + s];
        if (v2 > rv[tid] || (v2 == rv[tid] && i2 < ri[tid])) { rv[tid] = v2; ri[tid] = i2; }
      }
      __syncthreads();
    }
    if (tid == 0) { idx[((size_t)b * H_ + h) * KSEL + kk] = ri[0]; sL[ri[0]] = -INFINITY; }
    __syncthreads();
  }
}

// ---------------- memory-branch attention (fp32 ksh/vsh) ----------------
__global__ __launch_bounds__(256) void memattn_kernel(const unsigned short* __restrict__ qbf,
                                                      const float* __restrict__ ksh,
                                                      const float* __restrict__ vsh,
                                                      unsigned short* __restrict__ omem) {
  __shared__ float kl[8][128];
  __shared__ float vl[8][128];
  int tid = threadIdx.x;
  int b = blockIdx.z, h = blockIdx.y, t = blockIdx.x * 256 + tid;
  const float* ks = ksh + ((size_t)b * H_ + h) * KSEL * DH_;
  const float* vs = vsh + ((size_t)b * H_ + h) * KSEL * DH_;
#pragma unroll
  for (int r = 0; r < 4; ++r) {
    int i = tid + r * 256;
    ((float*)kl)[i] = ks[i];
    ((float*)vl)[i] = vs[i];
  }
  __syncthreads();
  float sc[8] = {0.f,0.f,0.f,0.f,0.f,0.f,0.f,0.f};
  const unsigned short* qr = qbf + (size_t)(b * T_ + t) * QKVSTR + h * DH_;
  for (int c = 0; c < 4; ++c) {
    const s16x8* qp = (const s16x8*)(qr + c * 32);
#pragma unroll
    for (int u = 0; u < 4; ++u) {
      s16x8 q8 = qp[u];
#pragma unroll
      for (int e = 0; e < 8; ++e) {
        float qv = bf2f((unsigned short)q8[e]);
        int d = c * 32 + u * 8 + e;
#pragma unroll
        for (int kk = 0; kk < 8; ++kk) sc[kk] += qv * kl[kk][d];
      }
    }
  }
  float sm[8], mx = -INFINITY;
#pragma unroll
  for (int kk = 0; kk < 8; ++kk) { sm[kk] = sc[kk] * kScale; mx = fmaxf(mx, sm[kk]); }
  float sum = 0.f;
#pragma unroll
  for (int kk = 0; kk < 8; ++kk) { sm[kk] = __expf(sm[kk] - mx); sum += sm[kk]; }
  float inv = 1.f / sum;
#pragma unroll
  for (int kk = 0; kk < 8; ++kk) sm[kk] *= inv;
  unsigned short* orow = omem + (size_t)(b * T_ + t) * D_ + h * DH_;
  for (int d = 0; d < 128; d += 4) {
    float o0 = 0.f, o1 = 0.f, o2 = 0.f, o3 = 0.f;
#pragma unroll
    for (int kk = 0; kk < 8; ++kk) {
      float w = sm[kk];
      o0 += w * vl[kk][d + 0];
      o1 += w * vl[kk][d + 1];
      o2 += w * vl[kk][d + 2];
      o3 += w * vl[kk][d + 3];
    }
    uint2 pk;
    pk.x = (unsigned)f2bf(o0) | ((unsigned)f2bf(o1) << 16);
    pk.y = (unsigned)f2bf(o2) | ((unsigned)f2bf(o3) << 16);
    *(uint2*)(orow + d) = pk;
  }
}

// ---------------- gate ----------------
__global__ __launch_bounds__(256) void gate_kernel(const float* __restrict__ hs,
                                                   const float* __restrict__ Wg,
                                                   const float* __restrict__ bg,
                                                   float* __restrict__ g) {
  int gid = blockIdx.x * 256 + threadIdx.x;
  int row = gid >> 6, lane = gid & 63;
  const float4* hr = (const float4*)(hs + (size_t)row * D_);
  const float4* wg4 = (const float4*)Wg;
  float acc = 0.f;
#pragma unroll
  for (int it = 0; it < 8; ++it) {
    float4 hv = hr[lane + it * 64], wv = wg4[lane + it * 64];
    acc += hv.x * wv.x + hv.y * wv.y + hv.z * wv.z + hv.w * wv.w;
  }
#pragma unroll
  for (int off = 1; off < 64; off <<= 1) acc += __shfl_xor(acc, off);
  if (lane == 0) g[row] = 1.f / (1.f + __expf(-(acc + bg[0])));
}

// ---------------- local sliding-window attention (GQA head-pair shared K/V; 8 waves) ----------------
__global__ __launch_bounds__(512) void localattn_kernel(const unsigned short* __restrict__ qbf,
                                                        const unsigned short* __restrict__ kbf,
                                                        const unsigned short* __restrict__ vbf,
                                                        unsigned short* __restrict__ olocal) {
  __shared__ __align__(16) unsigned short kL[2][32][128];
  __shared__ __align__(16) unsigned short vL[2][128][32];
  __shared__ __align__(16) unsigned short pl[8][16][40];
  const int tid = threadIdx.x;
  const int w = tid >> 6, lane = tid & 63;
  const int tb = blockIdx.x * 64;
  const int kvh = blockIdx.y, b = blockIdx.z;
  const int h = kvh * 2 + (w >> 2);
  const int t0 = tb + (w & 3) * 16;
  const int l15 = lane & 15, lg = lane >> 4;

  s16x8 qf[4];
  {
    const unsigned short* qb = qbf + ((size_t)(b * T_ + t0 + l15) * QKVSTR) + h * DH_ + lg * 8;
#pragma unroll
    for (int kb = 0; kb < 4; ++kb) qf[kb] = *(const s16x8*)(qb + kb * 32);
  }
  f32x4 of[8];
#pragma unroll
  for (int nb = 0; nb < 8; ++nb) of[nb] = fzero4();
  float m_r[4] = {-INFINITY, -INFINITY, -INFINITY, -INFINITY};
  float l_r[4] = {0.f, 0.f, 0.f, 0.f};

  int sstart = tb - (WWIN - 1);
  if (sstart < 0) sstart = 0;
  sstart &= ~31;
  const int slast = tb + 63;
  int wlow = t0 - (WWIN - 1);
  if (wlow < 0) wlow = 0;
  wlow &= ~31;
  const int whigh = t0 + 15;

  const int vk = tid & 15, vcg = (tid >> 4) & 15;
  auto STAGE = [&](int buf, int s0) {
    {
      int s = tid;
      int r = s >> 4, cs = s & 15;
      int cg = cs ^ (r & 7);
      const unsigned short* src = kbf + (size_t)(b * T_ + s0 + r) * QKVSTR + kvh * DH_ + cg * 8;
      __builtin_amdgcn_global_load_lds((const __attribute__((address_space(1))) void*)src,
          (__attribute__((address_space(3))) void*)((char*)&kL[buf][0][0] + w * 1024), 16, 0, 0);
    }
    if (tid < 256) {
      int r0 = 2 * vk;
      const unsigned short* vs = vbf + (size_t)(b * T_ + s0 + r0) * QKVSTR + kvh * DH_ + vcg * 8;
      s16x8 va = *(const s16x8*)vs;
      s16x8 vb2 = *(const s16x8*)(vs + QKVSTR);
      int q = vk >> 2;
      int colbase = 2 * (vk & 3);
#pragma unroll
      for (int e = 0; e < 8; ++e) {
        int c = vcg * 8 + e;
        int blk = q ^ ((c >> 2) & 3);
        unsigned int val = (unsigned int)(unsigned short)va[e] |
                           ((unsigned int)(unsigned short)vb2[e] << 16);
        *(unsigned int*)&vL[buf][c][blk * 8 + colbase] = val;
      }
    }
  };

  STAGE(0, sstart);
  int buf = 0;
  const int vp = (l15 >> 2) & 3;
  for (int s0 = sstart; s0 <= slast; s0 += 32, buf ^= 1) {
    __syncthreads();
    if (s0 + 32 <= slast) STAGE(buf ^ 1, s0 + 32);

    if (s0 >= wlow && s0 <= whigh) {
      f32x4 sc[2];
      sc[0] = fzero4(); sc[1] = fzero4();
#pragma unroll
      for (int cb = 0; cb < 2; ++cb) {
#pragma unroll
        for (int kb = 0; kb < 4; ++kb) {
          int r = cb * 16 + l15;
          int c = kb * 4 + lg;
          s16x8 kf = *(const s16x8*)((char*)&kL[buf][0][0] + r * 256 + ((c ^ (r & 7)) * 16));
          sc[cb] = __builtin_amdgcn_mfma_f32_16x16x32_bf16(qf[kb], kf, sc[cb], 0, 0, 0);
        }
      }
      float pv[2][4];
#pragma unroll
      for (int j = 0; j < 4; ++j) {
        int t = t0 + lg * 4 + j;
        int s_a = s0 + l15, s_b = s_a + 16;
        float va = sc[0][j] * kScale;
        float vb = sc[1][j] * kScale;
        va = (s_a <= t && s_a + (WWIN - 1) >= t) ? va : -INFINITY;
        vb = (s_b <= t && s_b + (WWIN - 1) >= t) ? vb : -INFINITY;
        float mx = fmaxf(va, vb);
#pragma unroll
        for (int off = 1; off < 16; off <<= 1) mx = fmaxf(mx, __shfl_xor(mx, off));
        float mn = fmaxf(m_r[j], mx);
        float alpha, pa, pb;
        if (mn == -INFINITY) { alpha = 1.f; pa = 0.f; pb = 0.f; }
        else {
          alpha = __expf(m_r[j] - mn);
          pa = __expf(va - mn);
          pb = __expf(vb - mn);
        }
        m_r[j] = mn;
        float rs = pa + pb;
#pragma unroll
        for (int off = 1; off < 16; off <<= 1) rs += __shfl_xor(rs, off);
        l_r[j] = l_r[j] * alpha + rs;
#pragma unroll
        for (int nb = 0; nb < 8; ++nb) of[nb][j] *= alpha;
        pv[0][j] = pa; pv[1][j] = pb;
      }
#pragma unroll
      for (int cb = 0; cb < 2; ++cb)
#pragma unroll
        for (int j = 0; j < 4; ++j)
          pl[w][lg * 4 + j][cb * 16 + l15] = f2bf(pv[cb][j]);
      asm volatile("s_waitcnt lgkmcnt(0)" ::: "memory");
      __builtin_amdgcn_sched_barrier(0);
      s16x8 pa8 = *(const s16x8*)&pl[w][l15][lg * 8];
#pragma unroll
      for (int nb = 0; nb < 8; ++nb) {
        int c = nb * 16 + l15;
        s16x8 vf = *(const s16x8*)&vL[buf][c][(lg ^ vp) * 8];
        of[nb] = __builtin_amdgcn_mfma_f32_16x16x32_bf16(pa8, vf, of[nb], 0, 0, 0);
      }
    }
  }

  float inv[4];
#pragma unroll
  for (int j = 0; j < 4; ++j) inv[j] = 1.f / l_r[j];
#pragma unroll
  for (int nb = 0; nb < 8; ++nb)
#pragma unroll
    for (int j = 0; j < 4; ++j) {
      int t = t0 + lg * 4 + j;
      olocal[(size_t)(b * T_ + t) * QKVSTR + h * DH_ + nb * 16 + l15] = f2bf(of[nb][j] * inv[j]);
    }
}

// ---------------- host launcher ----------------
extern "C" void kernel_launch(void* const* d_in, const int* in_sizes, int n_in,
                              void* d_out, int out_size, void* d_ws, size_t ws_size,
                              hipStream_t stream) {
  const float* hs   = (const float*)d_in[0];
  const float* cosp = (const float*)d_in[1];
  const float* sinp = (const float*)d_in[2];
  const float* mem  = (const float*)d_in[3];
  const float* Wq   = (const float*)d_in[4];
  const float* Wk   = (const float*)d_in[5];
  const float* Wv   = (const float*)d_in[6];
  const float* Wo   = (const float*)d_in[7];
  const float* Wg   = (const float*)d_in[8];
  const float* bg   = (const float*)d_in[9];
  float* out = (float*)d_out;

  char* p = (char*)d_ws;
  auto alloc = [&](size_t bytes) { char* r = p; p += (bytes + 255) & ~(size_t)255; return r; };
  float* qc     = (float*)alloc((size_t)B_ * H_ * DH_ * 4);
  float* gbuf   = (float*)alloc((size_t)BT * 4);
  float* zbuf   = (float*)alloc((size_t)B_ * H_ * D_ * 4);
  float* simbuf = (float*)alloc((size_t)B_ * H_ * NMEM * 4);
  int*   idxbuf = (int*)alloc((size_t)B_ * H_ * KSEL * 4);
  float* ksh    = (float*)alloc((size_t)B_ * H_ * KSEL * DH_ * 4);
  float* vsh    = (float*)alloc((size_t)B_ * H_ * KSEL * DH_ * 4);
  unsigned short* hs_bf   = (unsigned short*)alloc((size_t)BT * D_ * 2);       // -> o_mem bf16 later
  unsigned short* qkv_raw = (unsigned short*)alloc((size_t)BT * QKVSTR * 2);   // q|k|v merged; q -> o_local in place
  unsigned short* wbig    = (unsigned short*)alloc((size_t)2 * D_ * D_ * 2);   // Wq|Wk|Wv stack
  unsigned short* wo_bf   = (unsigned short*)alloc((size_t)D_ * D_ * 2);       // Wo bf16
  unsigned short* mem_bf  = (unsigned short*)alloc((size_t)B_ * NMEM * D_ * 2);
  float* crsr             = (float*)alloc((size_t)2 * B_ * DH_ * D_ * 4);      // Cr|Sr

  // C/S partials live in d_out (33.5 MB; fully rewritten by final GEMM)
  float* Cp = (float*)d_out;
  float* Sp = Cp + (size_t)8 * B_ * DH_ * D_;
  float* Cr = crsr;
  float* Sr = Cr + (size_t)B_ * DH_ * D_;
  unsigned short* omem_bf = hs_bf;

  // 1) merged conversions + merged QKV projection (256^2 8-phase)
  conv_hm_kernel<<<12288, 256, 0, stream>>>(hs, mem, hs_bf, mem_bf);
  conv_w4_kernel<<<12288, 256, 0, stream>>>(Wq, Wk, Wv, Wo, wbig, wo_bf);
  gemm256<0><<<dim3(QKVSTR / 256, BT / 256), 512, 0, stream>>>(hs_bf, wbig, QKVSTR, D_, D_, QKVSTR, qkv_raw, nullptr, nullptr, nullptr);

  // 2) merged in-place RoPE (q + k sections, one launch)
  rope_ip2_kernel<<<3072, 256, 0, stream>>>(qkv_raw, cosp, sinp);

  // 3) exact-fp32 selection path
  cs_kernel<<<dim3(D_ / 128, DH_ / 32, B_ * 8), 256, 0, stream>>>(hs, cosp, sinp, Cp, Sp);
  reduce_cs_kernel<<<(B_ * DH_ * D_ / 4) / 256, 256, 0, stream>>>((const float4*)Cp, (const float4*)Sp, (float4*)Cr, (float4*)Sr);
  qchunk_kernel<<<(B_ * H_ * DH_) / 4, 256, 0, stream>>>(Wq, Cr, Sr, qc);
  zk_kernel<<<dim3(D_ / 256, H_, B_), 256, 0, stream>>>(qc, Wk, zbuf);
  sim_kernel<<<dim3(NMEM / 16, B_), 256, 0, stream>>>(zbuf, mem, simbuf);
  topk_kernel<<<dim3(H_, B_), 256, 0, stream>>>(simbuf, idxbuf);

  // 4) gather-GEMM for selected K/V rows, then memory-branch attention -> o_mem bf16
  gsel_kernel<<<dim3(H_, B_), 256, 0, stream>>>(mem_bf, wbig + (size_t)D_ * D_, idxbuf, ksh, vsh);
  memattn_kernel<<<dim3(T_ / 256, H_, B_), 256, 0, stream>>>(qkv_raw, ksh, vsh, omem_bf);

  // 5) gate
  gate_kernel<<<BT / 4, 256, 0, stream>>>(hs, Wg, bg, gbuf);

  // 6) local sliding-window attention (GQA pair-shared K/V; writes o_local in place)
  localattn_kernel<<<dim3(T_ / 64, KV_, B_), 512, 0, stream>>>(qkv_raw, qkv_raw + D_, qkv_raw + D_ + KV_ * DH_, qkv_raw);

  // 7) Wo projection + final combine (256x128 tile -> 256 blocks, full machine)
  gemm256n<<<dim3(D_ / 128, BT / 256), 512, 0, stream>>>(qkv_raw, wo_bf, D_, D_, QKVSTR, D_, gbuf, omem_bf, out);
}